// Round 9
// baseline (478.089 us; speedup 1.0000x reference)
//
#include <hip/hip_runtime.h>

#define NROWS 2048
#define MDIM 128
#define NITER 50
#define PSTR 65     // Q^T staging stride (f32)
#define RSTR 136    // rhs/Wl row stride (bf16 units); 272B = 17*16 (b128-aligned)
#define XSTR 132    // f32 overlay stride (xb / coeff)

// LDS byte offsets (loop layout)
#define RH_B 0          // 64*136*2 = 17408
#define RM_B 17408
#define RL_B 34816
#define WL_B 52224      // 128*136*2 = 34816 -> 87040
#define RED_B 87040     // 8*64*20*4 = 40960 -> 128000
#define CNT_B 128000    // 64*16*4 = 4096 -> 132096
#define SMEM_BYTES 132096
// prologue overlays
#define QST_B 0         // 128*65*4 = 33280
#define PMAT_B 33792    // 64*128*8 = 65536 -> 99328
// epilogue overlays
#define XB_B 0          // 64*132*4 = 33792
#define CF_B 33792      // -> 67584

typedef unsigned short ushort_t;
typedef __attribute__((ext_vector_type(8))) short bf16x8;
typedef __attribute__((ext_vector_type(8))) unsigned short us8;
typedef __attribute__((ext_vector_type(4))) unsigned short us4;
typedef __attribute__((ext_vector_type(16))) float f32x16;

__device__ __forceinline__ ushort_t f2bf(float f) {
  unsigned int u = __builtin_bit_cast(unsigned int, f);
  unsigned int r = (u + 0x7fffu + ((u >> 16) & 1u)) >> 16;
  return (ushort_t)r;
}
__device__ __forceinline__ float bf2f(ushort_t h) {
  unsigned int u = ((unsigned int)h) << 16;
  return __builtin_bit_cast(float, u);
}

// ---------------------------------------------------------------------------
// mk_m64: M = I + 2*Vs*Vs^T (f64), X0 = 2I - M.  Optionally also writes
// VsT64[d][m] = (double)V[m][d] * (1/128) (same expression/bits as before).
// grid 256 = 8b x 32 (16x32 tiles). Per-element fma chain identical to R2-R8.
// ---------------------------------------------------------------------------
__global__ __launch_bounds__(256) void mk_m64(const float* __restrict__ V,
                                              double* __restrict__ M,
                                              double* __restrict__ X0,
                                              double* __restrict__ vs) {
  __shared__ double sA[16][130];
  __shared__ double sB[32][130];
  const int b = blockIdx.x >> 5, t = blockIdx.x & 31;
  const int i0 = (t >> 2) << 4, j0 = (t & 3) << 5;
  const float* Vb = V + b * MDIM * MDIM;
  const int tid = threadIdx.x;
  const double S = 1.0 / 128.0;
  for (int idx = tid; idx < 512; idx += 256) {
    const int r = idx >> 5, c4 = (idx & 31) << 2;
    float4 v = *(const float4*)(Vb + (i0 + r) * MDIM + c4);
    sA[r][c4 + 0] = v.x * S; sA[r][c4 + 1] = v.y * S;
    sA[r][c4 + 2] = v.z * S; sA[r][c4 + 3] = v.w * S;
  }
  for (int idx = tid; idx < 1024; idx += 256) {
    const int r = idx >> 5, c4 = (idx & 31) << 2;
    float4 w = *(const float4*)(Vb + (j0 + r) * MDIM + c4);
    sB[r][c4 + 0] = w.x * S; sB[r][c4 + 1] = w.y * S;
    sB[r][c4 + 2] = w.z * S; sB[r][c4 + 3] = w.w * S;
  }
  if (vs) {  // fused VsT64 chunk (512 elements per block)
    double* Tb = vs + b * 16384;
    const int base2 = t * 512;
    for (int k = tid; k < 512; k += 256) {
      const int idx = base2 + k;
      const int j = idx >> 7, c = idx & 127;
      Tb[idx] = (double)Vb[c * 128 + j] * (1.0 / 128.0);
    }
  }
  __syncthreads();
  const int tx = tid & 15, ty = tid >> 4;
  double acc0 = 0.0, acc1 = 0.0;
  for (int k = 0; k < 128; ++k) {
    const double a0 = sA[ty][k];
    const double b0 = sB[tx * 2 + 0][k], b1 = sB[tx * 2 + 1][k];
    acc0 = fma(a0, b0, acc0); acc1 = fma(a0, b1, acc1);
  }
  double* Mb = M + b * 16384;
  double* Xb = X0 + b * 16384;
#pragma unroll
  for (int j = 0; j < 2; ++j) {
    const int gi = i0 + ty, gj = j0 + tx * 2 + j;
    const double diag = (gi == gj) ? 1.0 : 0.0;
    const double mv = 2.0 * (j ? acc1 : acc0) + diag;
    Mb[gi * 128 + gj] = mv;
    Xb[gi * 128 + gj] = 2.0 * diag - mv;
  }
}

// ---------------------------------------------------------------------------
// ns_gemm64: C = A*B (B symmetric, read rows). mode>=1: C = 2*Xc - A*B.
// mode==2 (final): also emit bf16 limb split of W^T = fp32(I - Minv)^T
// (identical bits to the old prep_aux: same f64->f32->RNE-split chain).
// grid 256 = 8b x 32 (16x32 tiles). fma chain identical to R2-R8.
// ---------------------------------------------------------------------------
__global__ __launch_bounds__(256) void ns_gemm64(const double* __restrict__ A,
                                                 const double* __restrict__ B,
                                                 double* __restrict__ C,
                                                 const double* __restrict__ Xc,
                                                 int mode,
                                                 ushort_t* __restrict__ Whg,
                                                 ushort_t* __restrict__ Wmg,
                                                 ushort_t* __restrict__ Wlg) {
  __shared__ double sA[16][130];
  __shared__ double sB[32][130];
  const int b = blockIdx.x >> 5, t = blockIdx.x & 31;
  const int i0 = (t >> 2) << 4, j0 = (t & 3) << 5;
  const double* Ab = A + b * 16384;
  const double* Bb = B + b * 16384;
  const int tid = threadIdx.x;
  for (int idx = tid; idx < 1024; idx += 256) {
    const int r = idx >> 6, c2 = (idx & 63) << 1;
    *(double2*)&sA[r][c2] = *(const double2*)(Ab + (i0 + r) * 128 + c2);
  }
  for (int idx = tid; idx < 2048; idx += 256) {
    const int r = idx >> 6, c2 = (idx & 63) << 1;
    *(double2*)&sB[r][c2] = *(const double2*)(Bb + (j0 + r) * 128 + c2);
  }
  __syncthreads();
  const int tx = tid & 15, ty = tid >> 4;
  double acc0 = 0.0, acc1 = 0.0;
  for (int k = 0; k < 128; ++k) {
    const double a0 = sA[ty][k];
    const double b0 = sB[tx * 2 + 0][k], b1 = sB[tx * 2 + 1][k];
    acc0 = fma(a0, b0, acc0); acc1 = fma(a0, b1, acc1);
  }
  double* Cb = C + b * 16384;
  const double* Xcb = Xc + b * 16384;
#pragma unroll
  for (int j = 0; j < 2; ++j) {
    const int gi = i0 + ty, gj = j0 + tx * 2 + j;
    double v = (j ? acc1 : acc0);
    if (mode != 0) v = 2.0 * Xcb[gi * 128 + gj] - v;
    Cb[gi * 128 + gj] = v;
    if (mode == 2) {
      const double diag = (gi == gj) ? 1.0 : 0.0;
      const float wf = (float)(diag - v);
      const ushort_t h = f2bf(wf);
      const float r1 = wf - bf2f(h);
      const ushort_t m_ = f2bf(r1);
      const float r2 = r1 - bf2f(m_);
      const ushort_t l_ = f2bf(r2);
      Whg[b * 16384 + gj * 128 + gi] = h;   // transposed: A-ready [c][j]
      Wmg[b * 16384 + gj * 128 + gi] = m_;
      Wlg[b * 16384 + gj * 128 + gi] = l_;
    }
  }
}

// ---------------------------------------------------------------------------
// vst_prep (fallback if ws too small for fused VsT64 region)
// ---------------------------------------------------------------------------
__global__ __launch_bounds__(256) void vst_prep(const float* __restrict__ V,
                                                double* __restrict__ vs) {
  const int b = blockIdx.x >> 3, ch = blockIdx.x & 7;
  const float* Vb = V + b * 16384;
  double* Tb = vs + b * 16384;
  const int base = ch * 2048;
  for (int k = threadIdx.x; k < 2048; k += 256) {
    const int idx = base + k;
    const int j = idx >> 7, c = idx & 127;
    Tb[idx] = (double)Vb[c * 128 + j] * (1.0 / 128.0);
  }
}

// ---------------------------------------------------------------------------
// admm_mfma: persistent ADMM, f64 state + exact-split bf16 32x32x16 MFMA.
// grid 256 (1 block/CU, b = blockIdx&7 XCD-aligned), 1024 thr = 16 waves.
// Block = 64 rows. 8 C-tiles (4 ct x 2 nt) x 2 waves (K-split 64/64),
// partial C exchanged via LDS. A (W^T limbs): Wh/Wm VGPR-resident, Wl LDS.
// Frag maps: A[m=lane&31][k=8*(lane>>5)+j]; B[k][n=lane&31] same k;
// C: col(n)=lane&31, row(m)=(reg&3)+8*(reg>>2)+4*(lane>>5)  [m74/m101].
// P/state/epilogue f64 chains identical to R8 -> same trajectory class.
// ---------------------------------------------------------------------------
__global__ __launch_bounds__(1024, 4) void admm_mfma(const float* __restrict__ Q,
                                                     const float* __restrict__ V,
                                                     const ushort_t* __restrict__ Whg,
                                                     const ushort_t* __restrict__ Wmg,
                                                     const ushort_t* __restrict__ Wlg,
                                                     const double* __restrict__ VsT64,
                                                     float* __restrict__ out) {
  __shared__ __align__(16) char smem[SMEM_BYTES];
  const int tid = threadIdx.x;
  const int b = blockIdx.x & 7;
  const int n0 = (blockIdx.x >> 3) << 6;
  const int lane = tid & 63;
  const int w = tid >> 6;          // 0..15
  const int half = w >> 3;         // K-half (0: k<64, 1: k>=64)
  const int p = w & 7;             // tile id
  const int ct = p & 3, nt = p >> 2;
  const int l5 = lane & 31, kh = lane >> 5;
  const int nloc = 32 * nt + l5;            // n within block
  const int cB = 32 * ct + 16 * half + 4 * kh;  // c base of owned state
  const int k0 = 64 * half;

  const float* Qb = Q + ((size_t)(b * NROWS + n0)) * MDIM;
  float* outb = out + ((size_t)(b * NROWS + n0)) * MDIM;
  const ushort_t* WhB = Whg + b * 16384;
  const ushort_t* WmB = Wmg + b * 16384;
  const ushort_t* WlB = Wlg + b * 16384;

  float* QST = (float*)(smem + QST_B);
  double* pmat = (double*)(smem + PMAT_B);
  ushort_t* rhp = (ushort_t*)(smem + RH_B);
  ushort_t* rmp = (ushort_t*)(smem + RM_B);
  ushort_t* rlp = (ushort_t*)(smem + RL_B);
  ushort_t* wlp = (ushort_t*)(smem + WL_B);
  float* red = (float*)(smem + RED_B);
  float* sCnt = (float*)(smem + CNT_B);

  // ---- Phase 1: stage Q^T (f32): QST[d*65 + r], 64 rows
  for (int idx = tid; idx < 2048; idx += 1024) {
    const int r = idx >> 5, d4 = (idx & 31) << 2;
    const float4 q = *(const float4*)(Qb + r * 128 + d4);
    QST[(d4 + 0) * PSTR + r] = q.x;
    QST[(d4 + 1) * PSTR + r] = q.y;
    QST[(d4 + 2) * PSTR + r] = q.z;
    QST[(d4 + 3) * PSTR + r] = q.w;
  }
  __syncthreads();

  // ---- Phase 2: P = -2 Q Vs^T + lam/m in row-mapping (uniform s_loads; R7/R8 chain)
  {
    const int r2 = tid & 63;
    const int c8 = (tid >> 6) << 3;            // wave-uniform
    const double* vtb = VsT64 + b * 16384 + c8;
    double p8[8];
#pragma unroll
    for (int c = 0; c < 8; ++c) p8[c] = 0.0;
    for (int d = 0; d < 128; ++d) {
      const double a = (double)QST[d * PSTR + r2];
      const double* vt = vtb + d * 128;
#pragma unroll
      for (int c = 0; c < 8; ++c) p8[c] = fma(a, vt[c], p8[c]);
    }
    const double LAM = 0.1 / 128.0;
#pragma unroll
    for (int c = 0; c < 8; ++c) p8[c] = fma(-2.0, p8[c], LAM);
#pragma unroll
    for (int c = 0; c < 8; ++c) pmat[r2 * 128 + c8 + c] = p8[c];
  }
  __syncthreads();

  // ---- Phase 3: P to owned C-layout positions
  double pC[8];
#pragma unroll
  for (int s = 0; s < 8; ++s)
    pC[s] = pmat[nloc * 128 + cB + (s & 3) + 8 * (s >> 2)];
  __syncthreads();  // pmat/QST dead

  // ---- Phase 4: Wl -> LDS; Wh/Wm A-frags -> VGPRs
  for (int idx = tid; idx < 2048; idx += 1024) {
    const int c = idx >> 4, g = idx & 15;
    *(us8*)(wlp + c * RSTR + g * 8) = *(const us8*)(WlB + c * 128 + g * 8);
  }
  bf16x8 wfh[4], wfm[4];
#pragma unroll
  for (int s = 0; s < 4; ++s) {
    const int ko = (32 * ct + l5) * 128 + k0 + 16 * s + 8 * kh;
    wfh[s] = *(const bf16x8*)(WhB + ko);
    wfm[s] = *(const bf16x8*)(WmB + ko);
  }
  __syncthreads();

  // ---- ADMM loop
  double z[8], u[8];
#pragma unroll
  for (int s = 0; s < 8; ++s) { z[s] = 0.0; u[s] = 0.0; }
  const int rrow = nloc * RSTR;
  const int wlrow = (32 * ct + l5) * RSTR;
  float* slot = red + (p * 64 + lane) * 20;

  for (int it = 0; it < NITER; ++it) {
    // split r -> 3 bf16 limbs (RNE chain identical to R7/R8) -> LDS
    us4 h0, h1, m0, m1, l0, l1;
#pragma unroll
    for (int s = 0; s < 8; ++s) {
      const double rv = (z[s] - u[s]) - pC[s];
      const float rf = (float)rv;
      const ushort_t hh = f2bf(rf);
      const float r1 = rf - bf2f(hh);
      const ushort_t mm = f2bf(r1);
      const float r2 = r1 - bf2f(mm);
      const ushort_t ll = f2bf(r2);
      if (s < 4) { h0[s] = hh; m0[s] = mm; l0[s] = ll; }
      else       { h1[s - 4] = hh; m1[s - 4] = mm; l1[s - 4] = ll; }
    }
    *(us4*)(rhp + rrow + cB) = h0;  *(us4*)(rhp + rrow + cB + 8) = h1;
    *(us4*)(rmp + rrow + cB) = m0;  *(us4*)(rmp + rrow + cB + 8) = m1;
    *(us4*)(rlp + rrow + cB) = l0;  *(us4*)(rlp + rrow + cB + 8) = l1;
    __syncthreads();  // B1

    f32x16 acc;
#pragma unroll
    for (int i = 0; i < 16; ++i) acc[i] = 0.f;
#pragma unroll
    for (int s = 0; s < 4; ++s) {
      const int kq = k0 + 16 * s + 8 * kh;
      const bf16x8 bh = *(const bf16x8*)(rhp + rrow + kq);
      const bf16x8 bm = *(const bf16x8*)(rmp + rrow + kq);
      const bf16x8 bl = *(const bf16x8*)(rlp + rrow + kq);
      const bf16x8 al = *(const bf16x8*)(wlp + wlrow + kq);
      acc = __builtin_amdgcn_mfma_f32_32x32x16_bf16(wfh[s], bh, acc, 0, 0, 0);
      acc = __builtin_amdgcn_mfma_f32_32x32x16_bf16(wfh[s], bm, acc, 0, 0, 0);
      acc = __builtin_amdgcn_mfma_f32_32x32x16_bf16(wfm[s], bh, acc, 0, 0, 0);
      acc = __builtin_amdgcn_mfma_f32_32x32x16_bf16(wfm[s], bm, acc, 0, 0, 0);
      acc = __builtin_amdgcn_mfma_f32_32x32x16_bf16(wfh[s], bl, acc, 0, 0, 0);
      acc = __builtin_amdgcn_mfma_f32_32x32x16_bf16(al,     bh, acc, 0, 0, 0);
    }
    // K-split partial exchange: write partner's half (float2 x4, stride-20 slots)
    {
      const int o = 8 * (1 - half);
      float* dst = slot + (1 - half) * 8;
#pragma unroll
      for (int i = 0; i < 4; ++i) {
        float2 v2; v2.x = acc[o + 2 * i]; v2.y = acc[o + 2 * i + 1];
        *(float2*)(dst + 2 * i) = v2;
      }
    }
    __syncthreads();  // B2 (also guarantees all rhs reads complete)
    const float* rs = slot + half * 8;
    const int o2 = 8 * half;
#pragma unroll
    for (int s = 0; s < 8; ++s) {
      const float corr = acc[o2 + s] + rs[s];
      const double rv = (z[s] - u[s]) - pC[s];   // recompute (bit-identical)
      const double x = rv - (double)corr;
      const double y = x + u[s];
      const double zn = fmin(fmax(y, 0.0), 1.0);
      u[s] = y - zn;
      z[s] = zn;
    }
  }

  // ---- epilogue: threshold at C positions -> xbm matrix
  float* xbm = (float*)(smem + XB_B);
  {
    float4 x0, x1;
    x0.x = (z[0] > 0.5) ? 1.f : 0.f; x0.y = (z[1] > 0.5) ? 1.f : 0.f;
    x0.z = (z[2] > 0.5) ? 1.f : 0.f; x0.w = (z[3] > 0.5) ? 1.f : 0.f;
    x1.x = (z[4] > 0.5) ? 1.f : 0.f; x1.y = (z[5] > 0.5) ? 1.f : 0.f;
    x1.z = (z[6] > 0.5) ? 1.f : 0.f; x1.w = (z[7] > 0.5) ? 1.f : 0.f;
    *(float4*)(xbm + nloc * XSTR + cB) = x0;
    *(float4*)(xbm + nloc * XSTR + cB + 8) = x1;
  }
  __syncthreads();

  // counts + coeffs in row-mapping (chains identical to R8)
  const int n2 = tid >> 4, cg = tid & 15;
  float xb8[8];
  {
    const float4 a = *(const float4*)(xbm + n2 * XSTR + 8 * cg + 0);
    const float4 c2 = *(const float4*)(xbm + n2 * XSTR + 8 * cg + 4);
    xb8[0] = a.x; xb8[1] = a.y; xb8[2] = a.z; xb8[3] = a.w;
    xb8[4] = c2.x; xb8[5] = c2.y; xb8[6] = c2.z; xb8[7] = c2.w;
  }
  double cnt = 0.0;
#pragma unroll
  for (int c = 0; c < 8; ++c) cnt += (double)xb8[c];
  sCnt[n2 * 16 + cg] = (float)cnt;
  __syncthreads();
  double kk = 0.0;
#pragma unroll
  for (int g = 0; g < 16; ++g) kk += (double)sCnt[n2 * 16 + g];
  const double rkS = (1.0 / 128.0) / (kk + 1e-10);
  float* cf = (float*)(smem + CF_B);
  {
    float4 w0, w1;
    w0.x = (float)((double)xb8[0] * rkS); w0.y = (float)((double)xb8[1] * rkS);
    w0.z = (float)((double)xb8[2] * rkS); w0.w = (float)((double)xb8[3] * rkS);
    w1.x = (float)((double)xb8[4] * rkS); w1.y = (float)((double)xb8[5] * rkS);
    w1.z = (float)((double)xb8[6] * rkS); w1.w = (float)((double)xb8[7] * rkS);
    *(float4*)(cf + n2 * XSTR + 8 * cg + 0) = w0;
    *(float4*)(cf + n2 * XSTR + 8 * cg + 4) = w1;
  }
  __syncthreads();

  // out = coeffs . V (m-ascending chain; V via wave-uniform s_loads)
  const int n3 = tid & 63;
  const int c8o = (tid >> 6) << 3;     // wave-uniform
  const float* Vw = V + b * 16384 + c8o;
  float oa[8];
#pragma unroll
  for (int c = 0; c < 8; ++c) oa[c] = 0.f;
#pragma unroll 4
  for (int m4 = 0; m4 < 32; ++m4) {
    const float4 a4 = *(const float4*)(cf + n3 * XSTR + (m4 << 2));
#pragma unroll
    for (int mm = 0; mm < 4; ++mm) {
      const float* vp = Vw + ((m4 << 2) + mm) * 128;
      const float am = (mm == 0) ? a4.x : (mm == 1) ? a4.y : (mm == 2) ? a4.z : a4.w;
#pragma unroll
      for (int c = 0; c < 8; ++c) oa[c] = fmaf(am, vp[c], oa[c]);
    }
  }
#pragma unroll
  for (int q = 0; q < 2; ++q) {
    float4 o;
    o.x = oa[q * 4 + 0]; o.y = oa[q * 4 + 1];
    o.z = oa[q * 4 + 2]; o.w = oa[q * 4 + 3];
    *(float4*)(outb + n3 * 128 + c8o + q * 4) = o;
  }
}

// ---------------------------------------------------------------------------
extern "C" void kernel_launch(void* const* d_in, const int* in_sizes, int n_in,
                              void* d_out, int out_size, void* d_ws, size_t ws_size,
                              hipStream_t stream) {
  const float* Q = (const float*)d_in[0];
  const float* V = (const float*)d_in[1];
  float* out = (float*)d_out;
  double* ws = (double*)d_ws;
  double* Mw = ws;                // 1 MiB: M; recycled as bf16 W-limb arrays
  double* Xa = ws + 131072;
  double* Xb = ws + 262144;
  double* Tw = ws + 393216;       // NS temp; fallback VsT64 region
  ushort_t* Whg = (ushort_t*)Mw;
  ushort_t* Wmg = Whg + 131072;   // 256 KB each, 768 KB total (fits in Mw's 1 MiB)
  ushort_t* Wlg = Whg + 262144;

  const bool big = ws_size >= (size_t)(5 * 1024 * 1024);
  double* VsT = big ? (ws + 524288) : Tw;

  mk_m64<<<256, 256, 0, stream>>>(V, Mw, Xa, big ? VsT : (double*)nullptr);
  double* pa = Xa;
  double* pb = Xb;
  for (int i = 0; i < 3; ++i) {  // Newton-Schulz f64: residual ~6e-20
    ns_gemm64<<<256, 256, 0, stream>>>(pa, Mw, Tw, pa, 0, nullptr, nullptr, nullptr);
    ns_gemm64<<<256, 256, 0, stream>>>(Tw, pa, pb, pa, (i == 2) ? 2 : 1,
                                       Whg, Wmg, Wlg);
    double* tmp = pa; pa = pb; pb = tmp;
  }
  if (!big) vst_prep<<<64, 256, 0, stream>>>(V, Tw);  // Tw dead after last NS
  admm_mfma<<<256, 1024, 0, stream>>>(Q, V, Whg, Wmg, Wlg, VsT, out);
}

// Round 10
// 331.719 us; speedup vs baseline: 1.4412x; 1.4412x over previous
//
#include <hip/hip_runtime.h>

#define NROWS 2048
#define MDIM 128
#define NITER 50
#define PSTR 65     // Q^T staging stride (f32)
#define RSTR 136    // rhs/W-limb row stride (bf16); 272B, b128-aligned
#define XSTR 132    // f32 overlay stride (xb / coeff)

// LDS byte offsets (loop layout)
#define RH_B 0          // 64*136*2 = 17408
#define RM_B 17408
#define RL_B 34816      // -> 52224
#define WM_B 52224      // 128*136*2 = 34816 -> 87040
#define WL_B 87040      // -> 121856
#define CNT_B 121856    // 64*16*4 = 4096 -> 125952
#define SMEM_BYTES 125952
// prologue overlays
#define QST_B 0         // 128*65*4 = 33280
#define PMAT_B 33792    // 64*128*8 = 65536 -> 99328
// epilogue overlays
#define XB_B 0          // 64*132*4 = 33792
#define CF_B 33792      // -> 67584

typedef unsigned short ushort_t;
typedef __attribute__((ext_vector_type(8))) short bf16x8;
typedef __attribute__((ext_vector_type(8))) unsigned short us8;
typedef __attribute__((ext_vector_type(4))) unsigned short us4;
typedef __attribute__((ext_vector_type(4))) float f32x4;

__device__ __forceinline__ ushort_t f2bf(float f) {
  unsigned int u = __builtin_bit_cast(unsigned int, f);
  unsigned int r = (u + 0x7fffu + ((u >> 16) & 1u)) >> 16;
  return (ushort_t)r;
}
__device__ __forceinline__ float bf2f(ushort_t h) {
  unsigned int u = ((unsigned int)h) << 16;
  return __builtin_bit_cast(float, u);
}

// ---------------------------------------------------------------------------
// mk_m64: M = I + 2*Vs*Vs^T (f64), X0 = 2I - M; optional fused VsT64.
// (verbatim from R9 — verified, bit-identical chains)
// ---------------------------------------------------------------------------
__global__ __launch_bounds__(256) void mk_m64(const float* __restrict__ V,
                                              double* __restrict__ M,
                                              double* __restrict__ X0,
                                              double* __restrict__ vs) {
  __shared__ double sA[16][130];
  __shared__ double sB[32][130];
  const int b = blockIdx.x >> 5, t = blockIdx.x & 31;
  const int i0 = (t >> 2) << 4, j0 = (t & 3) << 5;
  const float* Vb = V + b * MDIM * MDIM;
  const int tid = threadIdx.x;
  const double S = 1.0 / 128.0;
  for (int idx = tid; idx < 512; idx += 256) {
    const int r = idx >> 5, c4 = (idx & 31) << 2;
    float4 v = *(const float4*)(Vb + (i0 + r) * MDIM + c4);
    sA[r][c4 + 0] = v.x * S; sA[r][c4 + 1] = v.y * S;
    sA[r][c4 + 2] = v.z * S; sA[r][c4 + 3] = v.w * S;
  }
  for (int idx = tid; idx < 1024; idx += 256) {
    const int r = idx >> 5, c4 = (idx & 31) << 2;
    float4 w = *(const float4*)(Vb + (j0 + r) * MDIM + c4);
    sB[r][c4 + 0] = w.x * S; sB[r][c4 + 1] = w.y * S;
    sB[r][c4 + 2] = w.z * S; sB[r][c4 + 3] = w.w * S;
  }
  if (vs) {
    double* Tb = vs + b * 16384;
    const int base2 = t * 512;
    for (int k = tid; k < 512; k += 256) {
      const int idx = base2 + k;
      const int j = idx >> 7, c = idx & 127;
      Tb[idx] = (double)Vb[c * 128 + j] * (1.0 / 128.0);
    }
  }
  __syncthreads();
  const int tx = tid & 15, ty = tid >> 4;
  double acc0 = 0.0, acc1 = 0.0;
  for (int k = 0; k < 128; ++k) {
    const double a0 = sA[ty][k];
    const double b0 = sB[tx * 2 + 0][k], b1 = sB[tx * 2 + 1][k];
    acc0 = fma(a0, b0, acc0); acc1 = fma(a0, b1, acc1);
  }
  double* Mb = M + b * 16384;
  double* Xb = X0 + b * 16384;
#pragma unroll
  for (int j = 0; j < 2; ++j) {
    const int gi = i0 + ty, gj = j0 + tx * 2 + j;
    const double diag = (gi == gj) ? 1.0 : 0.0;
    const double mv = 2.0 * (j ? acc1 : acc0) + diag;
    Mb[gi * 128 + gj] = mv;
    Xb[gi * 128 + gj] = 2.0 * diag - mv;
  }
}

// ---------------------------------------------------------------------------
// ns_gemm64 (verbatim from R9): mode 2 fuses the RNE W-limb split (same bits)
// ---------------------------------------------------------------------------
__global__ __launch_bounds__(256) void ns_gemm64(const double* __restrict__ A,
                                                 const double* __restrict__ B,
                                                 double* __restrict__ C,
                                                 const double* __restrict__ Xc,
                                                 int mode,
                                                 ushort_t* __restrict__ Whg,
                                                 ushort_t* __restrict__ Wmg,
                                                 ushort_t* __restrict__ Wlg) {
  __shared__ double sA[16][130];
  __shared__ double sB[32][130];
  const int b = blockIdx.x >> 5, t = blockIdx.x & 31;
  const int i0 = (t >> 2) << 4, j0 = (t & 3) << 5;
  const double* Ab = A + b * 16384;
  const double* Bb = B + b * 16384;
  const int tid = threadIdx.x;
  for (int idx = tid; idx < 1024; idx += 256) {
    const int r = idx >> 6, c2 = (idx & 63) << 1;
    *(double2*)&sA[r][c2] = *(const double2*)(Ab + (i0 + r) * 128 + c2);
  }
  for (int idx = tid; idx < 2048; idx += 256) {
    const int r = idx >> 6, c2 = (idx & 63) << 1;
    *(double2*)&sB[r][c2] = *(const double2*)(Bb + (j0 + r) * 128 + c2);
  }
  __syncthreads();
  const int tx = tid & 15, ty = tid >> 4;
  double acc0 = 0.0, acc1 = 0.0;
  for (int k = 0; k < 128; ++k) {
    const double a0 = sA[ty][k];
    const double b0 = sB[tx * 2 + 0][k], b1 = sB[tx * 2 + 1][k];
    acc0 = fma(a0, b0, acc0); acc1 = fma(a0, b1, acc1);
  }
  double* Cb = C + b * 16384;
  const double* Xcb = Xc + b * 16384;
#pragma unroll
  for (int j = 0; j < 2; ++j) {
    const int gi = i0 + ty, gj = j0 + tx * 2 + j;
    double v = (j ? acc1 : acc0);
    if (mode != 0) v = 2.0 * Xcb[gi * 128 + gj] - v;
    Cb[gi * 128 + gj] = v;
    if (mode == 2) {
      const double diag = (gi == gj) ? 1.0 : 0.0;
      const float wf = (float)(diag - v);
      const ushort_t h = f2bf(wf);
      const float r1 = wf - bf2f(h);
      const ushort_t m_ = f2bf(r1);
      const float r2 = r1 - bf2f(m_);
      const ushort_t l_ = f2bf(r2);
      Whg[b * 16384 + gj * 128 + gi] = h;   // transposed: A-ready [c][j]
      Wmg[b * 16384 + gj * 128 + gi] = m_;
      Wlg[b * 16384 + gj * 128 + gi] = l_;
    }
  }
}

// ---------------------------------------------------------------------------
// vst_prep (fallback if ws too small for fused VsT64 region)
// ---------------------------------------------------------------------------
__global__ __launch_bounds__(256) void vst_prep(const float* __restrict__ V,
                                                double* __restrict__ vs) {
  const int b = blockIdx.x >> 3, ch = blockIdx.x & 7;
  const float* Vb = V + b * 16384;
  double* Tb = vs + b * 16384;
  const int base = ch * 2048;
  for (int k = threadIdx.x; k < 2048; k += 256) {
    const int idx = base + k;
    const int j = idx >> 7, c = idx & 127;
    Tb[idx] = (double)Vb[c * 128 + j] * (1.0 / 128.0);
  }
}

// ---------------------------------------------------------------------------
// admm_mfma: persistent ADMM, f64 state + exact-split bf16 16x16x32 MFMA.
// R10 retile of R7: wave = 2 c-tiles x 1 n-tile -> B-frags read ONCE per ks
// (24 -> 12 B reads/wave); A: Wh VGPR-resident, Wm/Wl from LDS (+16 reads).
// grid 256 (1 block/CU, b = blockIdx&7), 1024 thr = 16 waves (4/SIMD).
// Wave w: nt = w&3, cpair = w>>2 -> ct{0,1} = 2*cpair + t. 8 state elems/lane.
// Truncation limb split for r (h+m+l == rf exactly; same dropped-term class).
// f64 P/state chains identical to R7 -> same trajectory class (absmax 0 anchor).
// ---------------------------------------------------------------------------
__global__ __launch_bounds__(1024, 4) void admm_mfma(const float* __restrict__ Q,
                                                     const float* __restrict__ V,
                                                     const ushort_t* __restrict__ Whg,
                                                     const ushort_t* __restrict__ Wmg,
                                                     const ushort_t* __restrict__ Wlg,
                                                     const double* __restrict__ VsT64,
                                                     float* __restrict__ out) {
  __shared__ __align__(16) char smem[SMEM_BYTES];
  const int tid = threadIdx.x;
  const int b = blockIdx.x & 7;
  const int n0 = (blockIdx.x >> 3) << 6;
  const int lane = tid & 63;
  const int w = tid >> 6;              // 0..15
  const int nt = w & 3, cpair = w >> 2;
  const int quad = lane >> 4, col16 = lane & 15;
  const int nloc = nt * 16 + col16;            // n within block (B col / C col)
  const int ct0 = cpair * 2, ct1 = ct0 + 1;
  const int rowA0 = ct0 * 16 + col16;          // A m-index, tile 0
  const int rowA1 = ct1 * 16 + col16;          // tile 1
  const int cB0 = ct0 * 16 + quad * 4;         // C row base, tile 0
  const int cB1 = cB0 + 16;

  const float* Qb = Q + ((size_t)(b * NROWS + n0)) * MDIM;
  float* outb = out + ((size_t)(b * NROWS + n0)) * MDIM;
  const ushort_t* WhB = Whg + b * 16384;
  const ushort_t* WmB = Wmg + b * 16384;
  const ushort_t* WlB = Wlg + b * 16384;

  float* QST = (float*)(smem + QST_B);
  double* pmat = (double*)(smem + PMAT_B);
  ushort_t* rhp = (ushort_t*)(smem + RH_B);
  ushort_t* rmp = (ushort_t*)(smem + RM_B);
  ushort_t* rlp = (ushort_t*)(smem + RL_B);
  ushort_t* wmp = (ushort_t*)(smem + WM_B);
  ushort_t* wlp = (ushort_t*)(smem + WL_B);
  float* sCnt = (float*)(smem + CNT_B);

  // ---- Phase 1: stage Q^T (f32): QST[d*65 + r], 64 rows
  for (int idx = tid; idx < 2048; idx += 1024) {
    const int r = idx >> 5, d4 = (idx & 31) << 2;
    const float4 q = *(const float4*)(Qb + r * 128 + d4);
    QST[(d4 + 0) * PSTR + r] = q.x;
    QST[(d4 + 1) * PSTR + r] = q.y;
    QST[(d4 + 2) * PSTR + r] = q.z;
    QST[(d4 + 3) * PSTR + r] = q.w;
  }
  __syncthreads();

  // ---- Phase 2: P = -2 Q Vs^T + lam/m (f64, chain identical to R7/R9)
  {
    const int r2 = tid & 63;
    const int c8 = (tid >> 6) << 3;            // wave-uniform
    const double* vtb = VsT64 + b * 16384 + c8;
    double p8[8];
#pragma unroll
    for (int c = 0; c < 8; ++c) p8[c] = 0.0;
    for (int d = 0; d < 128; ++d) {
      const double a = (double)QST[d * PSTR + r2];
      const double* vt = vtb + d * 128;
#pragma unroll
      for (int c = 0; c < 8; ++c) p8[c] = fma(a, vt[c], p8[c]);
    }
    const double LAM = 0.1 / 128.0;
#pragma unroll
    for (int c = 0; c < 8; ++c) p8[c] = fma(-2.0, p8[c], LAM);
#pragma unroll
    for (int c = 0; c < 8; ++c) pmat[r2 * 128 + c8 + c] = p8[c];
  }
  __syncthreads();

  // ---- Phase 3: P to owned C-layout positions (2 tiles x 4)
  double pC[2][4];
#pragma unroll
  for (int i = 0; i < 4; ++i) {
    pC[0][i] = pmat[nloc * 128 + cB0 + i];
    pC[1][i] = pmat[nloc * 128 + cB1 + i];
  }
  __syncthreads();  // pmat/QST dead

  // ---- Phase 4: Wm, Wl -> LDS (full K); Wh A-frags -> VGPRs
  for (int idx = tid; idx < 2048; idx += 1024) {
    const int c = idx >> 4, g = idx & 15;
    *(us8*)(wmp + c * RSTR + g * 8) = *(const us8*)(WmB + c * 128 + g * 8);
    *(us8*)(wlp + c * RSTR + g * 8) = *(const us8*)(WlB + c * 128 + g * 8);
  }
  bf16x8 wh0[4], wh1[4];
#pragma unroll
  for (int s = 0; s < 4; ++s) {
    const int kq = s * 32 + quad * 8;
    wh0[s] = *(const bf16x8*)(WhB + rowA0 * 128 + kq);
    wh1[s] = *(const bf16x8*)(WhB + rowA1 * 128 + kq);
  }
  __syncthreads();

  // ---- ADMM loop
  double z[2][4], u[2][4];
#pragma unroll
  for (int t = 0; t < 2; ++t)
#pragma unroll
    for (int i = 0; i < 4; ++i) { z[t][i] = 0.0; u[t][i] = 0.0; }
  const int rrow = nloc * RSTR;

  for (int it = 0; it < NITER; ++it) {
    // split r -> 3 bf16 limbs (truncation: h+m+l == rf exactly) -> LDS
#pragma unroll
    for (int t = 0; t < 2; ++t) {
      const int cb = t ? cB1 : cB0;
      us4 hh, mm2, ll;
#pragma unroll
      for (int i = 0; i < 4; ++i) {
        const double rv = (z[t][i] - u[t][i]) - pC[t][i];
        const float rf = (float)rv;
        const unsigned ub = __builtin_bit_cast(unsigned, rf);
        const float hf = __builtin_bit_cast(float, ub & 0xFFFF0000u);
        const float r1 = rf - hf;
        const unsigned ub1 = __builtin_bit_cast(unsigned, r1);
        const float mf = __builtin_bit_cast(float, ub1 & 0xFFFF0000u);
        const float r2 = r1 - mf;
        const unsigned ub2 = __builtin_bit_cast(unsigned, r2);
        hh[i] = (ushort_t)(ub >> 16);
        mm2[i] = (ushort_t)(ub1 >> 16);
        ll[i] = (ushort_t)(ub2 >> 16);
      }
      *(us4*)(rhp + rrow + cb) = hh;
      *(us4*)(rmp + rrow + cb) = mm2;
      *(us4*)(rlp + rrow + cb) = ll;
    }
    __syncthreads();  // B1

    f32x4 acc0 = {0.f, 0.f, 0.f, 0.f};
    f32x4 acc1 = {0.f, 0.f, 0.f, 0.f};
#pragma unroll
    for (int s = 0; s < 4; ++s) {
      const int kq = s * 32 + quad * 8;
      const bf16x8 bh = *(const bf16x8*)(rhp + rrow + kq);
      const bf16x8 bm = *(const bf16x8*)(rmp + rrow + kq);
      const bf16x8 bl = *(const bf16x8*)(rlp + rrow + kq);
      const bf16x8 am0 = *(const bf16x8*)(wmp + rowA0 * RSTR + kq);
      const bf16x8 al0 = *(const bf16x8*)(wlp + rowA0 * RSTR + kq);
      const bf16x8 am1 = *(const bf16x8*)(wmp + rowA1 * RSTR + kq);
      const bf16x8 al1 = *(const bf16x8*)(wlp + rowA1 * RSTR + kq);
      acc0 = __builtin_amdgcn_mfma_f32_16x16x32_bf16(wh0[s], bh, acc0, 0, 0, 0);
      acc0 = __builtin_amdgcn_mfma_f32_16x16x32_bf16(wh0[s], bm, acc0, 0, 0, 0);
      acc0 = __builtin_amdgcn_mfma_f32_16x16x32_bf16(am0,    bh, acc0, 0, 0, 0);
      acc0 = __builtin_amdgcn_mfma_f32_16x16x32_bf16(am0,    bm, acc0, 0, 0, 0);
      acc0 = __builtin_amdgcn_mfma_f32_16x16x32_bf16(wh0[s], bl, acc0, 0, 0, 0);
      acc0 = __builtin_amdgcn_mfma_f32_16x16x32_bf16(al0,    bh, acc0, 0, 0, 0);
      acc1 = __builtin_amdgcn_mfma_f32_16x16x32_bf16(wh1[s], bh, acc1, 0, 0, 0);
      acc1 = __builtin_amdgcn_mfma_f32_16x16x32_bf16(wh1[s], bm, acc1, 0, 0, 0);
      acc1 = __builtin_amdgcn_mfma_f32_16x16x32_bf16(am1,    bh, acc1, 0, 0, 0);
      acc1 = __builtin_amdgcn_mfma_f32_16x16x32_bf16(am1,    bm, acc1, 0, 0, 0);
      acc1 = __builtin_amdgcn_mfma_f32_16x16x32_bf16(wh1[s], bl, acc1, 0, 0, 0);
      acc1 = __builtin_amdgcn_mfma_f32_16x16x32_bf16(al1,    bh, acc1, 0, 0, 0);
    }
    __syncthreads();  // B2: all rhs reads done before next iteration's writes

#pragma unroll
    for (int t = 0; t < 2; ++t)
#pragma unroll
      for (int i = 0; i < 4; ++i) {
        const float corr = (t == 0) ? acc0[i] : acc1[i];
        const double rv = (z[t][i] - u[t][i]) - pC[t][i];  // recompute
        const double x = rv - (double)corr;
        const double y = x + u[t][i];
        const double zn = fmin(fmax(y, 0.0), 1.0);
        u[t][i] = y - zn;
        z[t][i] = zn;
      }
  }

  // ---- epilogue: threshold at C positions -> xbm matrix
  float* xbm = (float*)(smem + XB_B);
#pragma unroll
  for (int t = 0; t < 2; ++t) {
    const int cb = t ? cB1 : cB0;
    float4 o;
    o.x = (z[t][0] > 0.5) ? 1.f : 0.f;
    o.y = (z[t][1] > 0.5) ? 1.f : 0.f;
    o.z = (z[t][2] > 0.5) ? 1.f : 0.f;
    o.w = (z[t][3] > 0.5) ? 1.f : 0.f;
    *(float4*)(xbm + nloc * XSTR + cb) = o;
  }
  __syncthreads();

  // counts + coeffs in row-mapping (chains identical to R9)
  const int n2 = tid >> 4, cg = tid & 15;
  float xb8[8];
  {
    const float4 a = *(const float4*)(xbm + n2 * XSTR + 8 * cg + 0);
    const float4 c2 = *(const float4*)(xbm + n2 * XSTR + 8 * cg + 4);
    xb8[0] = a.x; xb8[1] = a.y; xb8[2] = a.z; xb8[3] = a.w;
    xb8[4] = c2.x; xb8[5] = c2.y; xb8[6] = c2.z; xb8[7] = c2.w;
  }
  double cnt = 0.0;
#pragma unroll
  for (int c = 0; c < 8; ++c) cnt += (double)xb8[c];
  sCnt[n2 * 16 + cg] = (float)cnt;
  __syncthreads();
  double kk = 0.0;
#pragma unroll
  for (int g = 0; g < 16; ++g) kk += (double)sCnt[n2 * 16 + g];
  const double rkS = (1.0 / 128.0) / (kk + 1e-10);
  float* cf = (float*)(smem + CF_B);
  {
    float4 w0, w1;
    w0.x = (float)((double)xb8[0] * rkS); w0.y = (float)((double)xb8[1] * rkS);
    w0.z = (float)((double)xb8[2] * rkS); w0.w = (float)((double)xb8[3] * rkS);
    w1.x = (float)((double)xb8[4] * rkS); w1.y = (float)((double)xb8[5] * rkS);
    w1.z = (float)((double)xb8[6] * rkS); w1.w = (float)((double)xb8[7] * rkS);
    *(float4*)(cf + n2 * XSTR + 8 * cg + 0) = w0;
    *(float4*)(cf + n2 * XSTR + 8 * cg + 4) = w1;
  }
  __syncthreads();

  // out = coeffs . V (m-ascending chain; V via wave-uniform s_loads)
  const int n3 = tid & 63;
  const int c8o = (tid >> 6) << 3;     // wave-uniform
  const float* Vw = V + b * 16384 + c8o;
  float oa[8];
#pragma unroll
  for (int c = 0; c < 8; ++c) oa[c] = 0.f;
#pragma unroll 4
  for (int m4 = 0; m4 < 32; ++m4) {
    const float4 a4 = *(const float4*)(cf + n3 * XSTR + (m4 << 2));
#pragma unroll
    for (int mm = 0; mm < 4; ++mm) {
      const float* vp = Vw + ((m4 << 2) + mm) * 128;
      const float am = (mm == 0) ? a4.x : (mm == 1) ? a4.y : (mm == 2) ? a4.z : a4.w;
#pragma unroll
      for (int c = 0; c < 8; ++c) oa[c] = fmaf(am, vp[c], oa[c]);
    }
  }
#pragma unroll
  for (int q = 0; q < 2; ++q) {
    float4 o;
    o.x = oa[q * 4 + 0]; o.y = oa[q * 4 + 1];
    o.z = oa[q * 4 + 2]; o.w = oa[q * 4 + 3];
    *(float4*)(outb + n3 * 128 + c8o + q * 4) = o;
  }
}

// ---------------------------------------------------------------------------
extern "C" void kernel_launch(void* const* d_in, const int* in_sizes, int n_in,
                              void* d_out, int out_size, void* d_ws, size_t ws_size,
                              hipStream_t stream) {
  const float* Q = (const float*)d_in[0];
  const float* V = (const float*)d_in[1];
  float* out = (float*)d_out;
  double* ws = (double*)d_ws;
  double* Mw = ws;                // 1 MiB: M; recycled as bf16 W-limb arrays
  double* Xa = ws + 131072;
  double* Xb = ws + 262144;
  double* Tw = ws + 393216;       // NS temp; fallback VsT64 region
  ushort_t* Whg = (ushort_t*)Mw;
  ushort_t* Wmg = Whg + 131072;
  ushort_t* Wlg = Whg + 262144;

  const bool big = ws_size >= (size_t)(5 * 1024 * 1024);
  double* VsT = big ? (ws + 524288) : Tw;

  mk_m64<<<256, 256, 0, stream>>>(V, Mw, Xa, big ? VsT : (double*)nullptr);
  double* pa = Xa;
  double* pb = Xb;
  for (int i = 0; i < 3; ++i) {  // Newton-Schulz f64: residual ~6e-20
    ns_gemm64<<<256, 256, 0, stream>>>(pa, Mw, Tw, pa, 0, nullptr, nullptr, nullptr);
    ns_gemm64<<<256, 256, 0, stream>>>(Tw, pa, pb, pa, (i == 2) ? 2 : 1,
                                       Whg, Wmg, Wlg);
    double* tmp = pa; pa = pb; pb = tmp;
  }
  if (!big) vst_prep<<<64, 256, 0, stream>>>(V, Tw);
  admm_mfma<<<256, 1024, 0, stream>>>(Q, V, Whg, Wmg, Wlg, VsT, out);
}

// Round 11
// 292.112 us; speedup vs baseline: 1.6367x; 1.1356x over previous
//
#include <hip/hip_runtime.h>

#define NROWS 2048
#define MDIM 128
#define NITER 50
#define PSTR 65     // Q^T staging stride (f32)
#define RSTR 136    // rhs/W-limb row stride (f16 units); 272B, b128-aligned
#define XSTR 132    // f32 overlay stride (xb / coeff)

// LDS byte offsets (loop layout)
#define RH_B 0          // 64*136*2 = 17408
#define RM_B 17408      // -> 34816
#define WM_B 34816      // 128*136*2 = 34816 -> 69632
#define CNT_B 69632     // 64*16*4 = 4096 -> 73728
// prologue overlays: QST 128*65*4 = 33280 at 0; pmat 64*128*8 = 65536 at 33792 -> 99328
#define QST_B 0
#define PMAT_B 33792
#define SMEM_BYTES 99328
// epilogue overlays
#define XB_B 0          // 64*132*4 = 33792
#define CF_B 33792      // -> 67584

typedef unsigned short ushort_t;
typedef __attribute__((ext_vector_type(8))) _Float16 f16x8;
typedef __attribute__((ext_vector_type(8))) unsigned short us8;
typedef __attribute__((ext_vector_type(4))) unsigned short us4;
typedef __attribute__((ext_vector_type(4))) float f32x4;

// ---------------------------------------------------------------------------
// mk_m64: M = I + 2*Vs*Vs^T (f64), X0 = 2I - M; optional fused VsT64.
// (verbatim from R9/R10 — verified, bit-identical chains)
// ---------------------------------------------------------------------------
__global__ __launch_bounds__(256) void mk_m64(const float* __restrict__ V,
                                              double* __restrict__ M,
                                              double* __restrict__ X0,
                                              double* __restrict__ vs) {
  __shared__ double sA[16][130];
  __shared__ double sB[32][130];
  const int b = blockIdx.x >> 5, t = blockIdx.x & 31;
  const int i0 = (t >> 2) << 4, j0 = (t & 3) << 5;
  const float* Vb = V + b * MDIM * MDIM;
  const int tid = threadIdx.x;
  const double S = 1.0 / 128.0;
  for (int idx = tid; idx < 512; idx += 256) {
    const int r = idx >> 5, c4 = (idx & 31) << 2;
    float4 v = *(const float4*)(Vb + (i0 + r) * MDIM + c4);
    sA[r][c4 + 0] = v.x * S; sA[r][c4 + 1] = v.y * S;
    sA[r][c4 + 2] = v.z * S; sA[r][c4 + 3] = v.w * S;
  }
  for (int idx = tid; idx < 1024; idx += 256) {
    const int r = idx >> 5, c4 = (idx & 31) << 2;
    float4 w = *(const float4*)(Vb + (j0 + r) * MDIM + c4);
    sB[r][c4 + 0] = w.x * S; sB[r][c4 + 1] = w.y * S;
    sB[r][c4 + 2] = w.z * S; sB[r][c4 + 3] = w.w * S;
  }
  if (vs) {
    double* Tb = vs + b * 16384;
    const int base2 = t * 512;
    for (int k = tid; k < 512; k += 256) {
      const int idx = base2 + k;
      const int j = idx >> 7, c = idx & 127;
      Tb[idx] = (double)Vb[c * 128 + j] * (1.0 / 128.0);
    }
  }
  __syncthreads();
  const int tx = tid & 15, ty = tid >> 4;
  double acc0 = 0.0, acc1 = 0.0;
  for (int k = 0; k < 128; ++k) {
    const double a0 = sA[ty][k];
    const double b0 = sB[tx * 2 + 0][k], b1 = sB[tx * 2 + 1][k];
    acc0 = fma(a0, b0, acc0); acc1 = fma(a0, b1, acc1);
  }
  double* Mb = M + b * 16384;
  double* Xb = X0 + b * 16384;
#pragma unroll
  for (int j = 0; j < 2; ++j) {
    const int gi = i0 + ty, gj = j0 + tx * 2 + j;
    const double diag = (gi == gj) ? 1.0 : 0.0;
    const double mv = 2.0 * (j ? acc1 : acc0) + diag;
    Mb[gi * 128 + gj] = mv;
    Xb[gi * 128 + gj] = 2.0 * diag - mv;
  }
}

// ---------------------------------------------------------------------------
// ns_gemm64: C = A*B (B symmetric). mode>=1: C = 2*Xc - A*B.
// mode==2: fused f16 2-limb split of W^T = fp32(I - Minv)^T, W pre-scaled
// by 1024 (exact pow2). h = f16(W*1024) RNE; r1 = exact residual; m = f16(r1).
// fma chain identical to R2-R10.
// ---------------------------------------------------------------------------
__global__ __launch_bounds__(256) void ns_gemm64(const double* __restrict__ A,
                                                 const double* __restrict__ B,
                                                 double* __restrict__ C,
                                                 const double* __restrict__ Xc,
                                                 int mode,
                                                 ushort_t* __restrict__ Whg,
                                                 ushort_t* __restrict__ Wmg) {
  __shared__ double sA[16][130];
  __shared__ double sB[32][130];
  const int b = blockIdx.x >> 5, t = blockIdx.x & 31;
  const int i0 = (t >> 2) << 4, j0 = (t & 3) << 5;
  const double* Ab = A + b * 16384;
  const double* Bb = B + b * 16384;
  const int tid = threadIdx.x;
  for (int idx = tid; idx < 1024; idx += 256) {
    const int r = idx >> 6, c2 = (idx & 63) << 1;
    *(double2*)&sA[r][c2] = *(const double2*)(Ab + (i0 + r) * 128 + c2);
  }
  for (int idx = tid; idx < 2048; idx += 256) {
    const int r = idx >> 6, c2 = (idx & 63) << 1;
    *(double2*)&sB[r][c2] = *(const double2*)(Bb + (j0 + r) * 128 + c2);
  }
  __syncthreads();
  const int tx = tid & 15, ty = tid >> 4;
  double acc0 = 0.0, acc1 = 0.0;
  for (int k = 0; k < 128; ++k) {
    const double a0 = sA[ty][k];
    const double b0 = sB[tx * 2 + 0][k], b1 = sB[tx * 2 + 1][k];
    acc0 = fma(a0, b0, acc0); acc1 = fma(a0, b1, acc1);
  }
  double* Cb = C + b * 16384;
  const double* Xcb = Xc + b * 16384;
#pragma unroll
  for (int j = 0; j < 2; ++j) {
    const int gi = i0 + ty, gj = j0 + tx * 2 + j;
    double v = (j ? acc1 : acc0);
    if (mode != 0) v = 2.0 * Xcb[gi * 128 + gj] - v;
    Cb[gi * 128 + gj] = v;
    if (mode == 2) {
      const double diag = (gi == gj) ? 1.0 : 0.0;
      const float wf = (float)(diag - v);
      const float wsc = wf * 1024.f;                 // exact pow2 scale
      const _Float16 h = (_Float16)wsc;              // RNE
      const float r1 = wsc - (float)h;               // exact residual
      const _Float16 m = (_Float16)r1;
      Whg[b * 16384 + gj * 128 + gi] = __builtin_bit_cast(ushort_t, h);
      Wmg[b * 16384 + gj * 128 + gi] = __builtin_bit_cast(ushort_t, m);
    }
  }
}

// ---------------------------------------------------------------------------
// vst_prep (fallback if ws too small for fused VsT64 region)
// ---------------------------------------------------------------------------
__global__ __launch_bounds__(256) void vst_prep(const float* __restrict__ V,
                                                double* __restrict__ vs) {
  const int b = blockIdx.x >> 3, ch = blockIdx.x & 7;
  const float* Vb = V + b * 16384;
  double* Tb = vs + b * 16384;
  const int base = ch * 2048;
  for (int k = threadIdx.x; k < 2048; k += 256) {
    const int idx = base + k;
    const int j = idx >> 7, c = idx & 127;
    Tb[idx] = (double)Vb[c * 128 + j] * (1.0 / 128.0);
  }
}

// ---------------------------------------------------------------------------
// admm_mfma: persistent ADMM, f64 state + f16 2-limb MFMA correction.
// R11 = R10 tiling (wave = 2 c-tiles x 1 n-tile) with f16 limbs:
// corr = (Wh*1024 + Wm*1024-resid)(rh + rm)/1024, terms hH,hM,mH (mM dropped
// at 2^-22|Wr| — same accepted class). Per wave/iter: 16 LDS reads (was 28),
// 24 MFMAs (was 48), 4 writes. Wh A-frags VGPR-resident; Wm from LDS.
// grid 256 (1 block/CU, b = blockIdx&7), 1024 thr = 16 waves (4/SIMD).
// f64 P/state chains identical to R10 -> same trajectory class (absmax-0 anchor).
// ---------------------------------------------------------------------------
__global__ __launch_bounds__(1024, 4) void admm_mfma(const float* __restrict__ Q,
                                                     const float* __restrict__ V,
                                                     const ushort_t* __restrict__ Whg,
                                                     const ushort_t* __restrict__ Wmg,
                                                     const double* __restrict__ VsT64,
                                                     float* __restrict__ out) {
  __shared__ __align__(16) char smem[SMEM_BYTES];
  const int tid = threadIdx.x;
  const int b = blockIdx.x & 7;
  const int n0 = (blockIdx.x >> 3) << 6;
  const int lane = tid & 63;
  const int w = tid >> 6;              // 0..15
  const int nt = w & 3, cpair = w >> 2;
  const int quad = lane >> 4, col16 = lane & 15;
  const int nloc = nt * 16 + col16;            // n within block
  const int ct0 = cpair * 2, ct1 = ct0 + 1;
  const int rowA0 = ct0 * 16 + col16;          // A m-index, tile 0
  const int rowA1 = ct1 * 16 + col16;          // tile 1
  const int cB0 = ct0 * 16 + quad * 4;         // C row base, tile 0
  const int cB1 = cB0 + 16;

  const float* Qb = Q + ((size_t)(b * NROWS + n0)) * MDIM;
  float* outb = out + ((size_t)(b * NROWS + n0)) * MDIM;
  const ushort_t* WhB = Whg + b * 16384;
  const ushort_t* WmB = Wmg + b * 16384;

  float* QST = (float*)(smem + QST_B);
  double* pmat = (double*)(smem + PMAT_B);
  ushort_t* rhp = (ushort_t*)(smem + RH_B);
  ushort_t* rmp = (ushort_t*)(smem + RM_B);
  ushort_t* wmp = (ushort_t*)(smem + WM_B);
  float* sCnt = (float*)(smem + CNT_B);

  // ---- Phase 1: stage Q^T (f32): QST[d*65 + r], 64 rows
  for (int idx = tid; idx < 2048; idx += 1024) {
    const int r = idx >> 5, d4 = (idx & 31) << 2;
    const float4 q = *(const float4*)(Qb + r * 128 + d4);
    QST[(d4 + 0) * PSTR + r] = q.x;
    QST[(d4 + 1) * PSTR + r] = q.y;
    QST[(d4 + 2) * PSTR + r] = q.z;
    QST[(d4 + 3) * PSTR + r] = q.w;
  }
  __syncthreads();

  // ---- Phase 2: P = -2 Q Vs^T + lam/m (f64, chain identical to R7-R10)
  {
    const int r2 = tid & 63;
    const int c8 = (tid >> 6) << 3;            // wave-uniform
    const double* vtb = VsT64 + b * 16384 + c8;
    double p8[8];
#pragma unroll
    for (int c = 0; c < 8; ++c) p8[c] = 0.0;
    for (int d = 0; d < 128; ++d) {
      const double a = (double)QST[d * PSTR + r2];
      const double* vt = vtb + d * 128;
#pragma unroll
      for (int c = 0; c < 8; ++c) p8[c] = fma(a, vt[c], p8[c]);
    }
    const double LAM = 0.1 / 128.0;
#pragma unroll
    for (int c = 0; c < 8; ++c) p8[c] = fma(-2.0, p8[c], LAM);
#pragma unroll
    for (int c = 0; c < 8; ++c) pmat[r2 * 128 + c8 + c] = p8[c];
  }
  __syncthreads();

  // ---- Phase 3: P to owned C-layout positions (2 tiles x 4)
  double pC[2][4];
#pragma unroll
  for (int i = 0; i < 4; ++i) {
    pC[0][i] = pmat[nloc * 128 + cB0 + i];
    pC[1][i] = pmat[nloc * 128 + cB1 + i];
  }
  __syncthreads();  // pmat/QST dead

  // ---- Phase 4: Wm -> LDS (full K); Wh A-frags -> VGPRs
  for (int idx = tid; idx < 2048; idx += 1024) {
    const int c = idx >> 4, g = idx & 15;
    *(us8*)(wmp + c * RSTR + g * 8) = *(const us8*)(WmB + c * 128 + g * 8);
  }
  f16x8 wh0[4], wh1[4];
#pragma unroll
  for (int s = 0; s < 4; ++s) {
    const int kq = s * 32 + quad * 8;
    wh0[s] = *(const f16x8*)(WhB + rowA0 * 128 + kq);
    wh1[s] = *(const f16x8*)(WhB + rowA1 * 128 + kq);
  }
  __syncthreads();

  // ---- ADMM loop
  double z[2][4], u[2][4];
#pragma unroll
  for (int t = 0; t < 2; ++t)
#pragma unroll
    for (int i = 0; i < 4; ++i) { z[t][i] = 0.0; u[t][i] = 0.0; }
  const int rrow = nloc * RSTR;
  const float RS = 1.f / 1024.f;   // exact pow2 rescale of corr

  for (int it = 0; it < NITER; ++it) {
    // split r -> 2 f16 limbs (h RNE; r1 exact; m RNE) -> LDS
#pragma unroll
    for (int t = 0; t < 2; ++t) {
      const int cb = t ? cB1 : cB0;
      us4 hh, mm2;
#pragma unroll
      for (int i = 0; i < 4; ++i) {
        const double rv = (z[t][i] - u[t][i]) - pC[t][i];
        const float rf = (float)rv;
        const _Float16 h = (_Float16)rf;
        const float r1 = rf - (float)h;
        const _Float16 m = (_Float16)r1;
        hh[i] = __builtin_bit_cast(ushort_t, h);
        mm2[i] = __builtin_bit_cast(ushort_t, m);
      }
      *(us4*)(rhp + rrow + cb) = hh;
      *(us4*)(rmp + rrow + cb) = mm2;
    }
    __syncthreads();  // B1

    f32x4 acc0 = {0.f, 0.f, 0.f, 0.f};
    f32x4 acc1 = {0.f, 0.f, 0.f, 0.f};
#pragma unroll
    for (int s = 0; s < 4; ++s) {
      const int kq = s * 32 + quad * 8;
      const f16x8 bh = *(const f16x8*)(rhp + rrow + kq);
      const f16x8 bm = *(const f16x8*)(rmp + rrow + kq);
      const f16x8 am0 = *(const f16x8*)(wmp + rowA0 * RSTR + kq);
      const f16x8 am1 = *(const f16x8*)(wmp + rowA1 * RSTR + kq);
      acc0 = __builtin_amdgcn_mfma_f32_16x16x32_f16(wh0[s], bh, acc0, 0, 0, 0);
      acc0 = __builtin_amdgcn_mfma_f32_16x16x32_f16(wh0[s], bm, acc0, 0, 0, 0);
      acc0 = __builtin_amdgcn_mfma_f32_16x16x32_f16(am0,    bh, acc0, 0, 0, 0);
      acc1 = __builtin_amdgcn_mfma_f32_16x16x32_f16(wh1[s], bh, acc1, 0, 0, 0);
      acc1 = __builtin_amdgcn_mfma_f32_16x16x32_f16(wh1[s], bm, acc1, 0, 0, 0);
      acc1 = __builtin_amdgcn_mfma_f32_16x16x32_f16(am1,    bh, acc1, 0, 0, 0);
    }
    __syncthreads();  // B2: all rhs reads done before next iteration's writes

#pragma unroll
    for (int t = 0; t < 2; ++t)
#pragma unroll
      for (int i = 0; i < 4; ++i) {
        const float corr = ((t == 0) ? acc0[i] : acc1[i]) * RS;
        const double rv = (z[t][i] - u[t][i]) - pC[t][i];  // recompute
        const double x = rv - (double)corr;
        const double y = x + u[t][i];
        const double zn = fmin(fmax(y, 0.0), 1.0);
        u[t][i] = y - zn;
        z[t][i] = zn;
      }
  }

  // ---- epilogue: threshold at C positions -> xbm matrix
  float* xbm = (float*)(smem + XB_B);
#pragma unroll
  for (int t = 0; t < 2; ++t) {
    const int cb = t ? cB1 : cB0;
    float4 o;
    o.x = (z[t][0] > 0.5) ? 1.f : 0.f;
    o.y = (z[t][1] > 0.5) ? 1.f : 0.f;
    o.z = (z[t][2] > 0.5) ? 1.f : 0.f;
    o.w = (z[t][3] > 0.5) ? 1.f : 0.f;
    *(float4*)(xbm + nloc * XSTR + cb) = o;
  }
  __syncthreads();

  // counts + coeffs in row-mapping (chains identical to R9/R10)
  const int n2 = tid >> 4, cg = tid & 15;
  float xb8[8];
  {
    const float4 a = *(const float4*)(xbm + n2 * XSTR + 8 * cg + 0);
    const float4 c2 = *(const float4*)(xbm + n2 * XSTR + 8 * cg + 4);
    xb8[0] = a.x; xb8[1] = a.y; xb8[2] = a.z; xb8[3] = a.w;
    xb8[4] = c2.x; xb8[5] = c2.y; xb8[6] = c2.z; xb8[7] = c2.w;
  }
  double cnt = 0.0;
#pragma unroll
  for (int c = 0; c < 8; ++c) cnt += (double)xb8[c];
  sCnt[n2 * 16 + cg] = (float)cnt;
  __syncthreads();
  double kk = 0.0;
#pragma unroll
  for (int g = 0; g < 16; ++g) kk += (double)sCnt[n2 * 16 + g];
  const double rkS = (1.0 / 128.0) / (kk + 1e-10);
  float* cf = (float*)(smem + CF_B);
  {
    float4 w0, w1;
    w0.x = (float)((double)xb8[0] * rkS); w0.y = (float)((double)xb8[1] * rkS);
    w0.z = (float)((double)xb8[2] * rkS); w0.w = (float)((double)xb8[3] * rkS);
    w1.x = (float)((double)xb8[4] * rkS); w1.y = (float)((double)xb8[5] * rkS);
    w1.z = (float)((double)xb8[6] * rkS); w1.w = (float)((double)xb8[7] * rkS);
    *(float4*)(cf + n2 * XSTR + 8 * cg + 0) = w0;
    *(float4*)(cf + n2 * XSTR + 8 * cg + 4) = w1;
  }
  __syncthreads();

  // out = coeffs . V (m-ascending chain; V via wave-uniform s_loads)
  const int n3 = tid & 63;
  const int c8o = (tid >> 6) << 3;     // wave-uniform
  const float* Vw = V + b * 16384 + c8o;
  float oa[8];
#pragma unroll
  for (int c = 0; c < 8; ++c) oa[c] = 0.f;
#pragma unroll 4
  for (int m4 = 0; m4 < 32; ++m4) {
    const float4 a4 = *(const float4*)(cf + n3 * XSTR + (m4 << 2));
#pragma unroll
    for (int mm = 0; mm < 4; ++mm) {
      const float* vp = Vw + ((m4 << 2) + mm) * 128;
      const float am = (mm == 0) ? a4.x : (mm == 1) ? a4.y : (mm == 2) ? a4.z : a4.w;
#pragma unroll
      for (int c = 0; c < 8; ++c) oa[c] = fmaf(am, vp[c], oa[c]);
    }
  }
#pragma unroll
  for (int q = 0; q < 2; ++q) {
    float4 o;
    o.x = oa[q * 4 + 0]; o.y = oa[q * 4 + 1];
    o.z = oa[q * 4 + 2]; o.w = oa[q * 4 + 3];
    *(float4*)(outb + n3 * 128 + c8o + q * 4) = o;
  }
}

// ---------------------------------------------------------------------------
extern "C" void kernel_launch(void* const* d_in, const int* in_sizes, int n_in,
                              void* d_out, int out_size, void* d_ws, size_t ws_size,
                              hipStream_t stream) {
  const float* Q = (const float*)d_in[0];
  const float* V = (const float*)d_in[1];
  float* out = (float*)d_out;
  double* ws = (double*)d_ws;
  double* Mw = ws;                // 1 MiB: M; recycled as f16 W-limb arrays
  double* Xa = ws + 131072;
  double* Xb = ws + 262144;
  double* Tw = ws + 393216;       // NS temp; fallback VsT64 region
  ushort_t* Whg = (ushort_t*)Mw;
  ushort_t* Wmg = Whg + 131072;   // 256 KB each (fits Mw's 1 MiB)

  const bool big = ws_size >= (size_t)(5 * 1024 * 1024);
  double* VsT = big ? (ws + 524288) : Tw;

  mk_m64<<<256, 256, 0, stream>>>(V, Mw, Xa, big ? VsT : (double*)nullptr);
  double* pa = Xa;
  double* pb = Xb;
  for (int i = 0; i < 3; ++i) {  // Newton-Schulz f64: residual ~6e-20
    ns_gemm64<<<256, 256, 0, stream>>>(pa, Mw, Tw, pa, 0, nullptr, nullptr);
    ns_gemm64<<<256, 256, 0, stream>>>(Tw, pa, pb, pa, (i == 2) ? 2 : 1,
                                       Whg, Wmg);
    double* tmp = pa; pa = pb; pb = tmp;
  }
  if (!big) vst_prep<<<64, 256, 0, stream>>>(V, Tw);
  admm_mfma<<<256, 1024, 0, stream>>>(Q, V, Whg, Wmg, VsT, out);
}

// Round 12
// 271.732 us; speedup vs baseline: 1.7594x; 1.0750x over previous
//
#include <hip/hip_runtime.h>

#define NROWS 2048
#define MDIM 128
#define NITER 50
#define PSTR 65     // Q^T staging stride (f32)
#define RSTR 136    // rhs/W-limb row stride (f16 units); 272B, b128-aligned
#define XSTR 132    // f32 overlay stride (xb / coeff)

// LDS byte offsets (loop layout): double-buffered rhs limbs + Wm + counts
#define RH0_B 0         // 64*136*2 = 17408
#define RM0_B 17408     // -> 34816
#define RH1_B 34816     // -> 52224
#define RM1_B 52224     // -> 69632
#define BUF_STRIDE 34816
#define WM_B 69632      // 128*136*2 = 34816 -> 104448
#define CNT_B 104448    // 64*16*4 = 4096 -> 108544
#define SMEM_BYTES 108544
// prologue overlays: QST 128*65*4 = 33280 at 0; pmat 64*128*8 at 33792 -> 99328
#define QST_B 0
#define PMAT_B 33792
// epilogue overlays
#define XB_B 0          // 64*132*4 = 33792
#define CF_B 33792      // -> 67584

typedef unsigned short ushort_t;
typedef __attribute__((ext_vector_type(8))) _Float16 f16x8;
typedef __attribute__((ext_vector_type(8))) unsigned short us8;
typedef __attribute__((ext_vector_type(4))) unsigned short us4;
typedef __attribute__((ext_vector_type(4))) float f32x4;

// ---------------------------------------------------------------------------
// mk_m64: M = I + 2*Vs*Vs^T (f64), X0 = 2I - M; optional fused VsT64.
// (verbatim from R9-R11 — verified, bit-identical chains)
// ---------------------------------------------------------------------------
__global__ __launch_bounds__(256) void mk_m64(const float* __restrict__ V,
                                              double* __restrict__ M,
                                              double* __restrict__ X0,
                                              double* __restrict__ vs) {
  __shared__ double sA[16][130];
  __shared__ double sB[32][130];
  const int b = blockIdx.x >> 5, t = blockIdx.x & 31;
  const int i0 = (t >> 2) << 4, j0 = (t & 3) << 5;
  const float* Vb = V + b * MDIM * MDIM;
  const int tid = threadIdx.x;
  const double S = 1.0 / 128.0;
  for (int idx = tid; idx < 512; idx += 256) {
    const int r = idx >> 5, c4 = (idx & 31) << 2;
    float4 v = *(const float4*)(Vb + (i0 + r) * MDIM + c4);
    sA[r][c4 + 0] = v.x * S; sA[r][c4 + 1] = v.y * S;
    sA[r][c4 + 2] = v.z * S; sA[r][c4 + 3] = v.w * S;
  }
  for (int idx = tid; idx < 1024; idx += 256) {
    const int r = idx >> 5, c4 = (idx & 31) << 2;
    float4 w = *(const float4*)(Vb + (j0 + r) * MDIM + c4);
    sB[r][c4 + 0] = w.x * S; sB[r][c4 + 1] = w.y * S;
    sB[r][c4 + 2] = w.z * S; sB[r][c4 + 3] = w.w * S;
  }
  if (vs) {
    double* Tb = vs + b * 16384;
    const int base2 = t * 512;
    for (int k = tid; k < 512; k += 256) {
      const int idx = base2 + k;
      const int j = idx >> 7, c = idx & 127;
      Tb[idx] = (double)Vb[c * 128 + j] * (1.0 / 128.0);
    }
  }
  __syncthreads();
  const int tx = tid & 15, ty = tid >> 4;
  double acc0 = 0.0, acc1 = 0.0;
  for (int k = 0; k < 128; ++k) {
    const double a0 = sA[ty][k];
    const double b0 = sB[tx * 2 + 0][k], b1 = sB[tx * 2 + 1][k];
    acc0 = fma(a0, b0, acc0); acc1 = fma(a0, b1, acc1);
  }
  double* Mb = M + b * 16384;
  double* Xb = X0 + b * 16384;
#pragma unroll
  for (int j = 0; j < 2; ++j) {
    const int gi = i0 + ty, gj = j0 + tx * 2 + j;
    const double diag = (gi == gj) ? 1.0 : 0.0;
    const double mv = 2.0 * (j ? acc1 : acc0) + diag;
    Mb[gi * 128 + gj] = mv;
    Xb[gi * 128 + gj] = 2.0 * diag - mv;
  }
}

// ---------------------------------------------------------------------------
// ns_gemm64: C = A*B (B symmetric). mode>=1: C = 2*Xc - A*B.
// mode==2: fused f16 2-limb split of W^T (W*1024, exact pow2 scale).
// R12: k-pair double2 LDS reads; per-accumulator fma order still k-ascending
// -> bit-identical results to R11's version.
// ---------------------------------------------------------------------------
__global__ __launch_bounds__(256) void ns_gemm64(const double* __restrict__ A,
                                                 const double* __restrict__ B,
                                                 double* __restrict__ C,
                                                 const double* __restrict__ Xc,
                                                 int mode,
                                                 ushort_t* __restrict__ Whg,
                                                 ushort_t* __restrict__ Wmg) {
  __shared__ double sA[16][130];
  __shared__ double sB[32][130];
  const int b = blockIdx.x >> 5, t = blockIdx.x & 31;
  const int i0 = (t >> 2) << 4, j0 = (t & 3) << 5;
  const double* Ab = A + b * 16384;
  const double* Bb = B + b * 16384;
  const int tid = threadIdx.x;
  for (int idx = tid; idx < 1024; idx += 256) {
    const int r = idx >> 6, c2 = (idx & 63) << 1;
    *(double2*)&sA[r][c2] = *(const double2*)(Ab + (i0 + r) * 128 + c2);
  }
  for (int idx = tid; idx < 2048; idx += 256) {
    const int r = idx >> 6, c2 = (idx & 63) << 1;
    *(double2*)&sB[r][c2] = *(const double2*)(Bb + (j0 + r) * 128 + c2);
  }
  __syncthreads();
  const int tx = tid & 15, ty = tid >> 4;
  double acc0 = 0.0, acc1 = 0.0;
  for (int k = 0; k < 128; k += 2) {
    const double2 a2  = *(const double2*)&sA[ty][k];
    const double2 b0p = *(const double2*)&sB[tx * 2 + 0][k];
    const double2 b1p = *(const double2*)&sB[tx * 2 + 1][k];
    acc0 = fma(a2.x, b0p.x, acc0); acc1 = fma(a2.x, b1p.x, acc1);
    acc0 = fma(a2.y, b0p.y, acc0); acc1 = fma(a2.y, b1p.y, acc1);
  }
  double* Cb = C + b * 16384;
  const double* Xcb = Xc + b * 16384;
#pragma unroll
  for (int j = 0; j < 2; ++j) {
    const int gi = i0 + ty, gj = j0 + tx * 2 + j;
    double v = (j ? acc1 : acc0);
    if (mode != 0) v = 2.0 * Xcb[gi * 128 + gj] - v;
    Cb[gi * 128 + gj] = v;
    if (mode == 2) {
      const double diag = (gi == gj) ? 1.0 : 0.0;
      const float wf = (float)(diag - v);
      const float wsc = wf * 1024.f;                 // exact pow2 scale
      const _Float16 h = (_Float16)wsc;              // RNE
      const float r1 = wsc - (float)h;               // exact residual
      const _Float16 m = (_Float16)r1;
      Whg[b * 16384 + gj * 128 + gi] = __builtin_bit_cast(ushort_t, h);
      Wmg[b * 16384 + gj * 128 + gi] = __builtin_bit_cast(ushort_t, m);
    }
  }
}

// ---------------------------------------------------------------------------
// vst_prep (fallback if ws too small for fused VsT64 region)
// ---------------------------------------------------------------------------
__global__ __launch_bounds__(256) void vst_prep(const float* __restrict__ V,
                                                double* __restrict__ vs) {
  const int b = blockIdx.x >> 3, ch = blockIdx.x & 7;
  const float* Vb = V + b * 16384;
  double* Tb = vs + b * 16384;
  const int base = ch * 2048;
  for (int k = threadIdx.x; k < 2048; k += 256) {
    const int idx = base + k;
    const int j = idx >> 7, c = idx & 127;
    Tb[idx] = (double)Vb[c * 128 + j] * (1.0 / 128.0);
  }
}

// ---------------------------------------------------------------------------
// admm_mfma: persistent ADMM, f64 state + f16 2-limb MFMA correction.
// R12 = R11 with: (1) double-buffered rhs limbs -> ONE barrier per iteration
// (buffers alternate; collective-barrier ordering makes writes of buf_{k+1}
// and buf_{k+2}=buf_k race-free vs reads of buf_k); (2) r64 kept in registers
// (drops the f64 recompute). Arithmetic values identical to R11's chains.
// grid 256 (1 block/CU, b = blockIdx&7), 1024 thr = 16 waves (4/SIMD).
// ---------------------------------------------------------------------------
__global__ __launch_bounds__(1024, 4) void admm_mfma(const float* __restrict__ Q,
                                                     const float* __restrict__ V,
                                                     const ushort_t* __restrict__ Whg,
                                                     const ushort_t* __restrict__ Wmg,
                                                     const double* __restrict__ VsT64,
                                                     float* __restrict__ out) {
  __shared__ __align__(16) char smem[SMEM_BYTES];
  const int tid = threadIdx.x;
  const int b = blockIdx.x & 7;
  const int n0 = (blockIdx.x >> 3) << 6;
  const int lane = tid & 63;
  const int w = tid >> 6;              // 0..15
  const int nt = w & 3, cpair = w >> 2;
  const int quad = lane >> 4, col16 = lane & 15;
  const int nloc = nt * 16 + col16;            // n within block
  const int ct0 = cpair * 2, ct1 = ct0 + 1;
  const int rowA0 = ct0 * 16 + col16;          // A m-index, tile 0
  const int rowA1 = ct1 * 16 + col16;          // tile 1
  const int cB0 = ct0 * 16 + quad * 4;         // C row base, tile 0
  const int cB1 = cB0 + 16;

  const float* Qb = Q + ((size_t)(b * NROWS + n0)) * MDIM;
  float* outb = out + ((size_t)(b * NROWS + n0)) * MDIM;
  const ushort_t* WhB = Whg + b * 16384;
  const ushort_t* WmB = Wmg + b * 16384;

  float* QST = (float*)(smem + QST_B);
  double* pmat = (double*)(smem + PMAT_B);
  ushort_t* wmp = (ushort_t*)(smem + WM_B);
  float* sCnt = (float*)(smem + CNT_B);

  // ---- Phase 1: stage Q^T (f32): QST[d*65 + r], 64 rows
  for (int idx = tid; idx < 2048; idx += 1024) {
    const int r = idx >> 5, d4 = (idx & 31) << 2;
    const float4 q = *(const float4*)(Qb + r * 128 + d4);
    QST[(d4 + 0) * PSTR + r] = q.x;
    QST[(d4 + 1) * PSTR + r] = q.y;
    QST[(d4 + 2) * PSTR + r] = q.z;
    QST[(d4 + 3) * PSTR + r] = q.w;
  }
  __syncthreads();

  // ---- Phase 2: P = -2 Q Vs^T + lam/m (f64, chain identical to R7-R11)
  {
    const int r2 = tid & 63;
    const int c8 = (tid >> 6) << 3;            // wave-uniform
    const double* vtb = VsT64 + b * 16384 + c8;
    double p8[8];
#pragma unroll
    for (int c = 0; c < 8; ++c) p8[c] = 0.0;
    for (int d = 0; d < 128; ++d) {
      const double a = (double)QST[d * PSTR + r2];
      const double* vt = vtb + d * 128;
#pragma unroll
      for (int c = 0; c < 8; ++c) p8[c] = fma(a, vt[c], p8[c]);
    }
    const double LAM = 0.1 / 128.0;
#pragma unroll
    for (int c = 0; c < 8; ++c) p8[c] = fma(-2.0, p8[c], LAM);
#pragma unroll
    for (int c = 0; c < 8; ++c) pmat[r2 * 128 + c8 + c] = p8[c];
  }
  __syncthreads();

  // ---- Phase 3: P to owned C-layout positions (2 tiles x 4)
  double pC[2][4];
#pragma unroll
  for (int i = 0; i < 4; ++i) {
    pC[0][i] = pmat[nloc * 128 + cB0 + i];
    pC[1][i] = pmat[nloc * 128 + cB1 + i];
  }
  __syncthreads();  // pmat/QST dead

  // ---- Phase 4: Wm -> LDS (full K); Wh A-frags -> VGPRs
  for (int idx = tid; idx < 2048; idx += 1024) {
    const int c = idx >> 4, g = idx & 15;
    *(us8*)(wmp + c * RSTR + g * 8) = *(const us8*)(WmB + c * 128 + g * 8);
  }
  f16x8 wh0[4], wh1[4];
#pragma unroll
  for (int s = 0; s < 4; ++s) {
    const int kq = s * 32 + quad * 8;
    wh0[s] = *(const f16x8*)(WhB + rowA0 * 128 + kq);
    wh1[s] = *(const f16x8*)(WhB + rowA1 * 128 + kq);
  }
  __syncthreads();

  // ---- ADMM loop: ONE barrier per iteration (double-buffered rhs limbs)
  double z[2][4], u[2][4], r64[2][4];
#pragma unroll
  for (int t = 0; t < 2; ++t)
#pragma unroll
    for (int i = 0; i < 4; ++i) { z[t][i] = 0.0; u[t][i] = 0.0; }
  const int rrow = nloc * RSTR;
  const float RS = 1.f / 1024.f;   // exact pow2 rescale of corr

  for (int it = 0; it < NITER; ++it) {
    const int boff = (it & 1) * BUF_STRIDE;
    ushort_t* rhp = (ushort_t*)(smem + RH0_B + boff);
    ushort_t* rmp = (ushort_t*)(smem + RM0_B + boff);
    // split r -> 2 f16 limbs (h RNE; r1 exact; m RNE) -> LDS
#pragma unroll
    for (int t = 0; t < 2; ++t) {
      const int cb = t ? cB1 : cB0;
      us4 hh, mm2;
#pragma unroll
      for (int i = 0; i < 4; ++i) {
        const double rv = (z[t][i] - u[t][i]) - pC[t][i];
        r64[t][i] = rv;
        const float rf = (float)rv;
        const _Float16 h = (_Float16)rf;
        const float r1 = rf - (float)h;
        const _Float16 m = (_Float16)r1;
        hh[i] = __builtin_bit_cast(ushort_t, h);
        mm2[i] = __builtin_bit_cast(ushort_t, m);
      }
      *(us4*)(rhp + rrow + cb) = hh;
      *(us4*)(rmp + rrow + cb) = mm2;
    }
    __syncthreads();  // single barrier: all buf_it writes visible

    f32x4 acc0 = {0.f, 0.f, 0.f, 0.f};
    f32x4 acc1 = {0.f, 0.f, 0.f, 0.f};
#pragma unroll
    for (int s = 0; s < 4; ++s) {
      const int kq = s * 32 + quad * 8;
      const f16x8 bh = *(const f16x8*)(rhp + rrow + kq);
      const f16x8 bm = *(const f16x8*)(rmp + rrow + kq);
      const f16x8 am0 = *(const f16x8*)(wmp + rowA0 * RSTR + kq);
      const f16x8 am1 = *(const f16x8*)(wmp + rowA1 * RSTR + kq);
      acc0 = __builtin_amdgcn_mfma_f32_16x16x32_f16(wh0[s], bh, acc0, 0, 0, 0);
      acc0 = __builtin_amdgcn_mfma_f32_16x16x32_f16(wh0[s], bm, acc0, 0, 0, 0);
      acc0 = __builtin_amdgcn_mfma_f32_16x16x32_f16(am0,    bh, acc0, 0, 0, 0);
      acc1 = __builtin_amdgcn_mfma_f32_16x16x32_f16(wh1[s], bh, acc1, 0, 0, 0);
      acc1 = __builtin_amdgcn_mfma_f32_16x16x32_f16(wh1[s], bm, acc1, 0, 0, 0);
      acc1 = __builtin_amdgcn_mfma_f32_16x16x32_f16(am1,    bh, acc1, 0, 0, 0);
    }
    // no second barrier: next iteration writes the OTHER buffer; writes to
    // this buffer again only after the NEXT barrier (all waves' reads done).

#pragma unroll
    for (int t = 0; t < 2; ++t)
#pragma unroll
      for (int i = 0; i < 4; ++i) {
        const float corr = ((t == 0) ? acc0[i] : acc1[i]) * RS;
        const double x = r64[t][i] - (double)corr;
        const double y = x + u[t][i];
        const double zn = fmin(fmax(y, 0.0), 1.0);
        u[t][i] = y - zn;
        z[t][i] = zn;
      }
  }

  // ---- epilogue: threshold at C positions -> xbm matrix
  // (xbm overlays buf0; safe: last buf0 reads were iter 48, sequenced before
  //  barrier 49 which every wave passed before reaching here)
  float* xbm = (float*)(smem + XB_B);
#pragma unroll
  for (int t = 0; t < 2; ++t) {
    const int cb = t ? cB1 : cB0;
    float4 o;
    o.x = (z[t][0] > 0.5) ? 1.f : 0.f;
    o.y = (z[t][1] > 0.5) ? 1.f : 0.f;
    o.z = (z[t][2] > 0.5) ? 1.f : 0.f;
    o.w = (z[t][3] > 0.5) ? 1.f : 0.f;
    *(float4*)(xbm + nloc * XSTR + cb) = o;
  }
  __syncthreads();

  // counts + coeffs in row-mapping (chains identical to R9-R11)
  const int n2 = tid >> 4, cg = tid & 15;
  float xb8[8];
  {
    const float4 a = *(const float4*)(xbm + n2 * XSTR + 8 * cg + 0);
    const float4 c2 = *(const float4*)(xbm + n2 * XSTR + 8 * cg + 4);
    xb8[0] = a.x; xb8[1] = a.y; xb8[2] = a.z; xb8[3] = a.w;
    xb8[4] = c2.x; xb8[5] = c2.y; xb8[6] = c2.z; xb8[7] = c2.w;
  }
  double cnt = 0.0;
#pragma unroll
  for (int c = 0; c < 8; ++c) cnt += (double)xb8[c];
  sCnt[n2 * 16 + cg] = (float)cnt;
  __syncthreads();
  double kk = 0.0;
#pragma unroll
  for (int g = 0; g < 16; ++g) kk += (double)sCnt[n2 * 16 + g];
  const double rkS = (1.0 / 128.0) / (kk + 1e-10);
  float* cf = (float*)(smem + CF_B);
  {
    float4 w0, w1;
    w0.x = (float)((double)xb8[0] * rkS); w0.y = (float)((double)xb8[1] * rkS);
    w0.z = (float)((double)xb8[2] * rkS); w0.w = (float)((double)xb8[3] * rkS);
    w1.x = (float)((double)xb8[4] * rkS); w1.y = (float)((double)xb8[5] * rkS);
    w1.z = (float)((double)xb8[6] * rkS); w1.w = (float)((double)xb8[7] * rkS);
    *(float4*)(cf + n2 * XSTR + 8 * cg + 0) = w0;
    *(float4*)(cf + n2 * XSTR + 8 * cg + 4) = w1;
  }
  __syncthreads();

  // out = coeffs . V (m-ascending chain; V via wave-uniform s_loads)
  const int n3 = tid & 63;
  const int c8o = (tid >> 6) << 3;     // wave-uniform
  const float* Vw = V + b * 16384 + c8o;
  float oa[8];
#pragma unroll
  for (int c = 0; c < 8; ++c) oa[c] = 0.f;
#pragma unroll 4
  for (int m4 = 0; m4 < 32; ++m4) {
    const float4 a4 = *(const float4*)(cf + n3 * XSTR + (m4 << 2));
#pragma unroll
    for (int mm = 0; mm < 4; ++mm) {
      const float* vp = Vw + ((m4 << 2) + mm) * 128;
      const float am = (mm == 0) ? a4.x : (mm == 1) ? a4.y : (mm == 2) ? a4.z : a4.w;
#pragma unroll
      for (int c = 0; c < 8; ++c) oa[c] = fmaf(am, vp[c], oa[c]);
    }
  }
#pragma unroll
  for (int q = 0; q < 2; ++q) {
    float4 o;
    o.x = oa[q * 4 + 0]; o.y = oa[q * 4 + 1];
    o.z = oa[q * 4 + 2]; o.w = oa[q * 4 + 3];
    *(float4*)(outb + n3 * 128 + c8o + q * 4) = o;
  }
}

// ---------------------------------------------------------------------------
extern "C" void kernel_launch(void* const* d_in, const int* in_sizes, int n_in,
                              void* d_out, int out_size, void* d_ws, size_t ws_size,
                              hipStream_t stream) {
  const float* Q = (const float*)d_in[0];
  const float* V = (const float*)d_in[1];
  float* out = (float*)d_out;
  double* ws = (double*)d_ws;
  double* Mw = ws;                // 1 MiB: M; recycled as f16 W-limb arrays
  double* Xa = ws + 131072;
  double* Xb = ws + 262144;
  double* Tw = ws + 393216;       // NS temp; fallback VsT64 region
  ushort_t* Whg = (ushort_t*)Mw;
  ushort_t* Wmg = Whg + 131072;   // 256 KB each (fits Mw's 1 MiB)

  const bool big = ws_size >= (size_t)(5 * 1024 * 1024);
  double* VsT = big ? (ws + 524288) : Tw;

  mk_m64<<<256, 256, 0, stream>>>(V, Mw, Xa, big ? VsT : (double*)nullptr);
  double* pa = Xa;
  double* pb = Xb;
  // Newton-Schulz f64, 2 iterations: residual ||E||^8 ~ 5e-10 — far below the
  // accepted f16-split corr-error class (absmax-0 across 4 corr variants).
  for (int i = 0; i < 2; ++i) {
    ns_gemm64<<<256, 256, 0, stream>>>(pa, Mw, Tw, pa, 0, nullptr, nullptr);
    ns_gemm64<<<256, 256, 0, stream>>>(Tw, pa, pb, pa, (i == 1) ? 2 : 1,
                                       Whg, Wmg);
    double* tmp = pa; pa = pb; pb = tmp;
  }
  if (!big) vst_prep<<<64, 256, 0, stream>>>(V, Tw);
  admm_mfma<<<256, 1024, 0, stream>>>(Q, V, Whg, Wmg, VsT, out);
}

// Round 13
// 263.289 us; speedup vs baseline: 1.8158x; 1.0321x over previous
//
#include <hip/hip_runtime.h>

#define NROWS 2048
#define MDIM 128
#define NITER 50
#define PSTR 65     // Q^T staging stride (f32)
#define RSTR 136    // rhs/W-limb row stride (f16 units); 272B, b128-aligned
#define XSTR 132    // f32 overlay stride (xb / coeff)

// LDS byte offsets (loop layout): double-buffered rhs limbs + Wm + counts
#define RH0_B 0         // 64*136*2 = 17408
#define RM0_B 17408     // -> 34816
#define RH1_B 34816     // -> 52224
#define RM1_B 52224     // -> 69632
#define BUF_STRIDE 34816
#define WM_B 69632      // 128*136*2 = 34816 -> 104448
#define CNT_B 104448    // 64*16*4 = 4096 -> 108544
#define SMEM_BYTES 108544
// prologue overlays: QST 128*65*4 = 33280 at 0; pmat 64*128*8 at 33792 -> 99328
#define QST_B 0
#define PMAT_B 33792
// epilogue overlays
#define XB_B 0          // 64*132*4 = 33792
#define CF_B 33792      // -> 67584

typedef unsigned short ushort_t;
typedef __attribute__((ext_vector_type(8))) _Float16 f16x8;
typedef __attribute__((ext_vector_type(8))) unsigned short us8;
typedef __attribute__((ext_vector_type(4))) unsigned short us4;
typedef __attribute__((ext_vector_type(4))) float f32x4;

// ---------------------------------------------------------------------------
// mk_m64: M = I + 2*Vs*Vs^T (f64), X0 = 2I - M; optional fused VsT64.
// (verbatim from R9-R12 — verified, bit-identical chains)
// ---------------------------------------------------------------------------
__global__ __launch_bounds__(256) void mk_m64(const float* __restrict__ V,
                                              double* __restrict__ M,
                                              double* __restrict__ X0,
                                              double* __restrict__ vs) {
  __shared__ double sA[16][130];
  __shared__ double sB[32][130];
  const int b = blockIdx.x >> 5, t = blockIdx.x & 31;
  const int i0 = (t >> 2) << 4, j0 = (t & 3) << 5;
  const float* Vb = V + b * MDIM * MDIM;
  const int tid = threadIdx.x;
  const double S = 1.0 / 128.0;
  for (int idx = tid; idx < 512; idx += 256) {
    const int r = idx >> 5, c4 = (idx & 31) << 2;
    float4 v = *(const float4*)(Vb + (i0 + r) * MDIM + c4);
    sA[r][c4 + 0] = v.x * S; sA[r][c4 + 1] = v.y * S;
    sA[r][c4 + 2] = v.z * S; sA[r][c4 + 3] = v.w * S;
  }
  for (int idx = tid; idx < 1024; idx += 256) {
    const int r = idx >> 5, c4 = (idx & 31) << 2;
    float4 w = *(const float4*)(Vb + (j0 + r) * MDIM + c4);
    sB[r][c4 + 0] = w.x * S; sB[r][c4 + 1] = w.y * S;
    sB[r][c4 + 2] = w.z * S; sB[r][c4 + 3] = w.w * S;
  }
  if (vs) {
    double* Tb = vs + b * 16384;
    const int base2 = t * 512;
    for (int k = tid; k < 512; k += 256) {
      const int idx = base2 + k;
      const int j = idx >> 7, c = idx & 127;
      Tb[idx] = (double)Vb[c * 128 + j] * (1.0 / 128.0);
    }
  }
  __syncthreads();
  const int tx = tid & 15, ty = tid >> 4;
  double acc0 = 0.0, acc1 = 0.0;
  for (int k = 0; k < 128; ++k) {
    const double a0 = sA[ty][k];
    const double b0 = sB[tx * 2 + 0][k], b1 = sB[tx * 2 + 1][k];
    acc0 = fma(a0, b0, acc0); acc1 = fma(a0, b1, acc1);
  }
  double* Mb = M + b * 16384;
  double* Xb = X0 + b * 16384;
#pragma unroll
  for (int j = 0; j < 2; ++j) {
    const int gi = i0 + ty, gj = j0 + tx * 2 + j;
    const double diag = (gi == gj) ? 1.0 : 0.0;
    const double mv = 2.0 * (j ? acc1 : acc0) + diag;
    Mb[gi * 128 + gj] = mv;
    Xb[gi * 128 + gj] = 2.0 * diag - mv;
  }
}

// ---------------------------------------------------------------------------
// ns_gemm64: per-b 128x128 f64 GEMM over symmetric operands (reads B rows).
// mode 0: C = A*B
// mode 1: C = 2*Xc - A*B                       (NS linear step)
// mode 3: C = 3*I - 3*Xc + A*B                 (cubic-NS polynomial step)
// mode 2: C = A*B, plus fused f16 2-limb split of W^T = fp32(I - C)^T
//         (W pre-scaled by 1024, exact pow2; h RNE, exact residual, m RNE)
// k-pair double2 LDS reads; per-accumulator fma order k-ascending.
// ---------------------------------------------------------------------------
__global__ __launch_bounds__(256) void ns_gemm64(const double* __restrict__ A,
                                                 const double* __restrict__ B,
                                                 double* __restrict__ C,
                                                 const double* __restrict__ Xc,
                                                 int mode,
                                                 ushort_t* __restrict__ Whg,
                                                 ushort_t* __restrict__ Wmg) {
  __shared__ double sA[16][130];
  __shared__ double sB[32][130];
  const int b = blockIdx.x >> 5, t = blockIdx.x & 31;
  const int i0 = (t >> 2) << 4, j0 = (t & 3) << 5;
  const double* Ab = A + b * 16384;
  const double* Bb = B + b * 16384;
  const int tid = threadIdx.x;
  for (int idx = tid; idx < 1024; idx += 256) {
    const int r = idx >> 6, c2 = (idx & 63) << 1;
    *(double2*)&sA[r][c2] = *(const double2*)(Ab + (i0 + r) * 128 + c2);
  }
  for (int idx = tid; idx < 2048; idx += 256) {
    const int r = idx >> 6, c2 = (idx & 63) << 1;
    *(double2*)&sB[r][c2] = *(const double2*)(Bb + (j0 + r) * 128 + c2);
  }
  __syncthreads();
  const int tx = tid & 15, ty = tid >> 4;
  double acc0 = 0.0, acc1 = 0.0;
  for (int k = 0; k < 128; k += 2) {
    const double2 a2  = *(const double2*)&sA[ty][k];
    const double2 b0p = *(const double2*)&sB[tx * 2 + 0][k];
    const double2 b1p = *(const double2*)&sB[tx * 2 + 1][k];
    acc0 = fma(a2.x, b0p.x, acc0); acc1 = fma(a2.x, b1p.x, acc1);
    acc0 = fma(a2.y, b0p.y, acc0); acc1 = fma(a2.y, b1p.y, acc1);
  }
  double* Cb = C + b * 16384;
  const double* Xcb = Xc + b * 16384;
#pragma unroll
  for (int j = 0; j < 2; ++j) {
    const int gi = i0 + ty, gj = j0 + tx * 2 + j;
    const double diag = (gi == gj) ? 1.0 : 0.0;
    double v = (j ? acc1 : acc0);
    if (mode == 1) v = 2.0 * Xcb[gi * 128 + gj] - v;
    else if (mode == 3) v = 3.0 * diag - 3.0 * Xcb[gi * 128 + gj] + v;
    Cb[gi * 128 + gj] = v;
    if (mode == 2) {
      const float wf = (float)(diag - v);
      const float wsc = wf * 1024.f;                 // exact pow2 scale
      const _Float16 h = (_Float16)wsc;              // RNE
      const float r1 = wsc - (float)h;               // exact residual
      const _Float16 m = (_Float16)r1;
      Whg[b * 16384 + gj * 128 + gi] = __builtin_bit_cast(ushort_t, h);
      Wmg[b * 16384 + gj * 128 + gi] = __builtin_bit_cast(ushort_t, m);
    }
  }
}

// ---------------------------------------------------------------------------
// vst_prep (fallback if ws too small for fused VsT64 region)
// ---------------------------------------------------------------------------
__global__ __launch_bounds__(256) void vst_prep(const float* __restrict__ V,
                                                double* __restrict__ vs) {
  const int b = blockIdx.x >> 3, ch = blockIdx.x & 7;
  const float* Vb = V + b * 16384;
  double* Tb = vs + b * 16384;
  const int base = ch * 2048;
  for (int k = threadIdx.x; k < 2048; k += 256) {
    const int idx = base + k;
    const int j = idx >> 7, c = idx & 127;
    Tb[idx] = (double)Vb[c * 128 + j] * (1.0 / 128.0);
  }
}

// ---------------------------------------------------------------------------
// admm_mfma: persistent ADMM, f64 state + f16 2-limb MFMA correction.
// R13 = R12 with Wm tile-1 A-frags VGPR-resident (loop LDS reads 16 -> 12
// b128/wave/iter; Wm LDS kept for tile-0 reads). Single barrier per iter
// via double-buffered rhs limbs. Arithmetic chains identical to R12.
// grid 256 (1 block/CU, b = blockIdx&7), 1024 thr = 16 waves (4/SIMD).
// ---------------------------------------------------------------------------
__global__ __launch_bounds__(1024, 4) void admm_mfma(const float* __restrict__ Q,
                                                     const float* __restrict__ V,
                                                     const ushort_t* __restrict__ Whg,
                                                     const ushort_t* __restrict__ Wmg,
                                                     const double* __restrict__ VsT64,
                                                     float* __restrict__ out) {
  __shared__ __align__(16) char smem[SMEM_BYTES];
  const int tid = threadIdx.x;
  const int b = blockIdx.x & 7;
  const int n0 = (blockIdx.x >> 3) << 6;
  const int lane = tid & 63;
  const int w = tid >> 6;              // 0..15
  const int nt = w & 3, cpair = w >> 2;
  const int quad = lane >> 4, col16 = lane & 15;
  const int nloc = nt * 16 + col16;            // n within block
  const int ct0 = cpair * 2, ct1 = ct0 + 1;
  const int rowA0 = ct0 * 16 + col16;          // A m-index, tile 0
  const int rowA1 = ct1 * 16 + col16;          // tile 1
  const int cB0 = ct0 * 16 + quad * 4;         // C row base, tile 0
  const int cB1 = cB0 + 16;

  const float* Qb = Q + ((size_t)(b * NROWS + n0)) * MDIM;
  float* outb = out + ((size_t)(b * NROWS + n0)) * MDIM;
  const ushort_t* WhB = Whg + b * 16384;
  const ushort_t* WmB = Wmg + b * 16384;

  float* QST = (float*)(smem + QST_B);
  double* pmat = (double*)(smem + PMAT_B);
  ushort_t* wmp = (ushort_t*)(smem + WM_B);
  float* sCnt = (float*)(smem + CNT_B);

  // ---- Phase 1: stage Q^T (f32): QST[d*65 + r], 64 rows
  for (int idx = tid; idx < 2048; idx += 1024) {
    const int r = idx >> 5, d4 = (idx & 31) << 2;
    const float4 q = *(const float4*)(Qb + r * 128 + d4);
    QST[(d4 + 0) * PSTR + r] = q.x;
    QST[(d4 + 1) * PSTR + r] = q.y;
    QST[(d4 + 2) * PSTR + r] = q.z;
    QST[(d4 + 3) * PSTR + r] = q.w;
  }
  __syncthreads();

  // ---- Phase 2: P = -2 Q Vs^T + lam/m (f64, chain identical to R7-R12)
  {
    const int r2 = tid & 63;
    const int c8 = (tid >> 6) << 3;            // wave-uniform
    const double* vtb = VsT64 + b * 16384 + c8;
    double p8[8];
#pragma unroll
    for (int c = 0; c < 8; ++c) p8[c] = 0.0;
    for (int d = 0; d < 128; ++d) {
      const double a = (double)QST[d * PSTR + r2];
      const double* vt = vtb + d * 128;
#pragma unroll
      for (int c = 0; c < 8; ++c) p8[c] = fma(a, vt[c], p8[c]);
    }
    const double LAM = 0.1 / 128.0;
#pragma unroll
    for (int c = 0; c < 8; ++c) p8[c] = fma(-2.0, p8[c], LAM);
#pragma unroll
    for (int c = 0; c < 8; ++c) pmat[r2 * 128 + c8 + c] = p8[c];
  }
  __syncthreads();

  // ---- Phase 3: P to owned C-layout positions (2 tiles x 4)
  double pC[2][4];
#pragma unroll
  for (int i = 0; i < 4; ++i) {
    pC[0][i] = pmat[nloc * 128 + cB0 + i];
    pC[1][i] = pmat[nloc * 128 + cB1 + i];
  }
  __syncthreads();  // pmat/QST dead

  // ---- Phase 4: Wm -> LDS (tile-0 reads); Wh (both) + Wm tile-1 -> VGPRs
  for (int idx = tid; idx < 2048; idx += 1024) {
    const int c = idx >> 4, g = idx & 15;
    *(us8*)(wmp + c * RSTR + g * 8) = *(const us8*)(WmB + c * 128 + g * 8);
  }
  f16x8 wh0[4], wh1[4], wm1[4];
#pragma unroll
  for (int s = 0; s < 4; ++s) {
    const int kq = s * 32 + quad * 8;
    wh0[s] = *(const f16x8*)(WhB + rowA0 * 128 + kq);
    wh1[s] = *(const f16x8*)(WhB + rowA1 * 128 + kq);
    wm1[s] = *(const f16x8*)(WmB + rowA1 * 128 + kq);
  }
  __syncthreads();

  // ---- ADMM loop: ONE barrier per iteration (double-buffered rhs limbs)
  double z[2][4], u[2][4], r64[2][4];
#pragma unroll
  for (int t = 0; t < 2; ++t)
#pragma unroll
    for (int i = 0; i < 4; ++i) { z[t][i] = 0.0; u[t][i] = 0.0; }
  const int rrow = nloc * RSTR;
  const float RS = 1.f / 1024.f;   // exact pow2 rescale of corr

  for (int it = 0; it < NITER; ++it) {
    const int boff = (it & 1) * BUF_STRIDE;
    ushort_t* rhp = (ushort_t*)(smem + RH0_B + boff);
    ushort_t* rmp = (ushort_t*)(smem + RM0_B + boff);
    // split r -> 2 f16 limbs (h RNE; r1 exact; m RNE) -> LDS
#pragma unroll
    for (int t = 0; t < 2; ++t) {
      const int cb = t ? cB1 : cB0;
      us4 hh, mm2;
#pragma unroll
      for (int i = 0; i < 4; ++i) {
        const double rv = (z[t][i] - u[t][i]) - pC[t][i];
        r64[t][i] = rv;
        const float rf = (float)rv;
        const _Float16 h = (_Float16)rf;
        const float r1 = rf - (float)h;
        const _Float16 m = (_Float16)r1;
        hh[i] = __builtin_bit_cast(ushort_t, h);
        mm2[i] = __builtin_bit_cast(ushort_t, m);
      }
      *(us4*)(rhp + rrow + cb) = hh;
      *(us4*)(rmp + rrow + cb) = mm2;
    }
    __syncthreads();  // single barrier: all buf_it writes visible

    f32x4 acc0 = {0.f, 0.f, 0.f, 0.f};
    f32x4 acc1 = {0.f, 0.f, 0.f, 0.f};
#pragma unroll
    for (int s = 0; s < 4; ++s) {
      const int kq = s * 32 + quad * 8;
      const f16x8 bh = *(const f16x8*)(rhp + rrow + kq);
      const f16x8 bm = *(const f16x8*)(rmp + rrow + kq);
      const f16x8 am0 = *(const f16x8*)(wmp + rowA0 * RSTR + kq);
      acc0 = __builtin_amdgcn_mfma_f32_16x16x32_f16(wh0[s], bh, acc0, 0, 0, 0);
      acc0 = __builtin_amdgcn_mfma_f32_16x16x32_f16(wh0[s], bm, acc0, 0, 0, 0);
      acc0 = __builtin_amdgcn_mfma_f32_16x16x32_f16(am0,    bh, acc0, 0, 0, 0);
      acc1 = __builtin_amdgcn_mfma_f32_16x16x32_f16(wh1[s], bh, acc1, 0, 0, 0);
      acc1 = __builtin_amdgcn_mfma_f32_16x16x32_f16(wh1[s], bm, acc1, 0, 0, 0);
      acc1 = __builtin_amdgcn_mfma_f32_16x16x32_f16(wm1[s], bh, acc1, 0, 0, 0);
    }
    // no second barrier: next iteration writes the OTHER buffer; this buffer
    // is rewritten only after the NEXT barrier (all waves' reads done).

#pragma unroll
    for (int t = 0; t < 2; ++t)
#pragma unroll
      for (int i = 0; i < 4; ++i) {
        const float corr = ((t == 0) ? acc0[i] : acc1[i]) * RS;
        const double x = r64[t][i] - (double)corr;
        const double y = x + u[t][i];
        const double zn = fmin(fmax(y, 0.0), 1.0);
        u[t][i] = y - zn;
        z[t][i] = zn;
      }
  }

  // ---- epilogue: threshold at C positions -> xbm matrix
  float* xbm = (float*)(smem + XB_B);
#pragma unroll
  for (int t = 0; t < 2; ++t) {
    const int cb = t ? cB1 : cB0;
    float4 o;
    o.x = (z[t][0] > 0.5) ? 1.f : 0.f;
    o.y = (z[t][1] > 0.5) ? 1.f : 0.f;
    o.z = (z[t][2] > 0.5) ? 1.f : 0.f;
    o.w = (z[t][3] > 0.5) ? 1.f : 0.f;
    *(float4*)(xbm + nloc * XSTR + cb) = o;
  }
  __syncthreads();

  // counts + coeffs in row-mapping (chains identical to R9-R12)
  const int n2 = tid >> 4, cg = tid & 15;
  float xb8[8];
  {
    const float4 a = *(const float4*)(xbm + n2 * XSTR + 8 * cg + 0);
    const float4 c2 = *(const float4*)(xbm + n2 * XSTR + 8 * cg + 4);
    xb8[0] = a.x; xb8[1] = a.y; xb8[2] = a.z; xb8[3] = a.w;
    xb8[4] = c2.x; xb8[5] = c2.y; xb8[6] = c2.z; xb8[7] = c2.w;
  }
  double cnt = 0.0;
#pragma unroll
  for (int c = 0; c < 8; ++c) cnt += (double)xb8[c];
  sCnt[n2 * 16 + cg] = (float)cnt;
  __syncthreads();
  double kk = 0.0;
#pragma unroll
  for (int g = 0; g < 16; ++g) kk += (double)sCnt[n2 * 16 + g];
  const double rkS = (1.0 / 128.0) / (kk + 1e-10);
  float* cf = (float*)(smem + CF_B);
  {
    float4 w0, w1;
    w0.x = (float)((double)xb8[0] * rkS); w0.y = (float)((double)xb8[1] * rkS);
    w0.z = (float)((double)xb8[2] * rkS); w0.w = (float)((double)xb8[3] * rkS);
    w1.x = (float)((double)xb8[4] * rkS); w1.y = (float)((double)xb8[5] * rkS);
    w1.z = (float)((double)xb8[6] * rkS); w1.w = (float)((double)xb8[7] * rkS);
    *(float4*)(cf + n2 * XSTR + 8 * cg + 0) = w0;
    *(float4*)(cf + n2 * XSTR + 8 * cg + 4) = w1;
  }
  __syncthreads();

  // out = coeffs . V (m-ascending chain; V via wave-uniform s_loads)
  const int n3 = tid & 63;
  const int c8o = (tid >> 6) << 3;     // wave-uniform
  const float* Vw = V + b * 16384 + c8o;
  float oa[8];
#pragma unroll
  for (int c = 0; c < 8; ++c) oa[c] = 0.f;
#pragma unroll 4
  for (int m4 = 0; m4 < 32; ++m4) {
    const float4 a4 = *(const float4*)(cf + n3 * XSTR + (m4 << 2));
#pragma unroll
    for (int mm = 0; mm < 4; ++mm) {
      const float* vp = Vw + ((m4 << 2) + mm) * 128;
      const float am = (mm == 0) ? a4.x : (mm == 1) ? a4.y : (mm == 2) ? a4.z : a4.w;
#pragma unroll
      for (int c = 0; c < 8; ++c) oa[c] = fmaf(am, vp[c], oa[c]);
    }
  }
#pragma unroll
  for (int q = 0; q < 2; ++q) {
    float4 o;
    o.x = oa[q * 4 + 0]; o.y = oa[q * 4 + 1];
    o.z = oa[q * 4 + 2]; o.w = oa[q * 4 + 3];
    *(float4*)(outb + n3 * 128 + c8o + q * 4) = o;
  }
}

// ---------------------------------------------------------------------------
extern "C" void kernel_launch(void* const* d_in, const int* in_sizes, int n_in,
                              void* d_out, int out_size, void* d_ws, size_t ws_size,
                              hipStream_t stream) {
  const float* Q = (const float*)d_in[0];
  const float* V = (const float*)d_in[1];
  float* out = (float*)d_out;
  double* ws = (double*)d_ws;
  double* Mw = ws;                // 1 MiB: M; recycled as f16 W-limb arrays
  double* Xa = ws + 131072;       // X0
  double* Xb = ws + 262144;       // P3
  double* Tw = ws + 393216;       // T, then G3's dead C; fallback VsT64 region
  ushort_t* Whg = (ushort_t*)Mw;
  ushort_t* Wmg = Whg + 131072;   // 256 KB each (fits Mw's 1 MiB)

  const bool big = ws_size >= (size_t)(5 * 1024 * 1024);
  double* VsT = big ? (ws + 524288) : Tw;

  mk_m64<<<256, 256, 0, stream>>>(V, Mw, Xa, big ? VsT : (double*)nullptr);
  // Cubic Newton-Schulz, 3 GEMMs: residual ||E0||^3 ~ 7e-8 rel — below the
  // accepted f16-limb truncation class (2.4e-7 rel; absmax-0 across variants).
  // T  = 2M - M*M            (mode 1, Xc = M)
  ns_gemm64<<<256, 256, 0, stream>>>(Mw, Mw, Tw, Mw, 1, nullptr, nullptr);
  // P3 = 3I - 3T + T*T       (mode 3, Xc = T)
  ns_gemm64<<<256, 256, 0, stream>>>(Tw, Tw, Xb, Tw, 3, nullptr, nullptr);
  // Minv = X0 * P3 ; fused W f16-limb split (mode 2; C -> Tw is dead output)
  ns_gemm64<<<256, 256, 0, stream>>>(Xa, Xb, Tw, Xa, 2, Whg, Wmg);
  if (!big) vst_prep<<<64, 256, 0, stream>>>(V, Tw);  // overwrites dead Tw
  admm_mfma<<<256, 1024, 0, stream>>>(Q, V, Whg, Wmg, VsT, out);
}